// Round 1
// baseline (24827.533 us; speedup 1.0000x reference)
//
#include <hip/hip_runtime.h>
#include <math.h>

#define DM     1024
#define RANK   128
#define NCMP   16
#define NKNOW  32768
#define TOPK   8
#define NROWS  4096          // B*S
#define NEG_BIG -3.0e38f
#define TK_SPLIT 8
#define TK_KEYS (NKNOW / TK_SPLIT)   // 4096 keys per split

// ---------------- LayerNorm: one block (256 thr) per row of 1024 ----------------
__global__ __launch_bounds__(256) void ln_kernel(const float* __restrict__ x,
                                                 const float* __restrict__ g,
                                                 const float* __restrict__ b,
                                                 float* __restrict__ o) {
  __shared__ float red1[4], red2[4];
  const int row = blockIdx.x, t = threadIdx.x;
  const float4 v = reinterpret_cast<const float4*>(x + (size_t)row * DM)[t];
  float s = v.x + v.y + v.z + v.w;
#pragma unroll
  for (int m = 1; m <= 32; m <<= 1) s += __shfl_xor(s, m);
  if ((t & 63) == 0) red1[t >> 6] = s;
  __syncthreads();
  const float mu = (red1[0] + red1[1] + red1[2] + red1[3]) * (1.0f / DM);
  const float dx = v.x - mu, dy = v.y - mu, dz = v.z - mu, dw = v.w - mu;
  float ss = dx * dx + dy * dy + dz * dz + dw * dw;
#pragma unroll
  for (int m = 1; m <= 32; m <<= 1) ss += __shfl_xor(ss, m);
  if ((t & 63) == 0) red2[t >> 6] = ss;
  __syncthreads();
  const float var = (red2[0] + red2[1] + red2[2] + red2[3]) * (1.0f / DM);
  const float inv = rsqrtf(var + 1e-5f);
  const float4 g4 = reinterpret_cast<const float4*>(g)[t];
  const float4 b4 = reinterpret_cast<const float4*>(b)[t];
  float4 r;
  r.x = dx * inv * g4.x + b4.x;
  r.y = dy * inv * g4.y + b4.y;
  r.z = dz * inv * g4.z + b4.z;
  r.w = dw * inv * g4.w + b4.w;
  reinterpret_cast<float4*>(o + (size_t)row * DM)[t] = r;
}

// ---------------- Router softmax: w[row][0..15] = softmax(h[row] @ R) ----------------
// one block of 64 threads per row; R is [1024][16]
__global__ __launch_bounds__(64) void router_kernel(const float* __restrict__ h,
                                                    const float* __restrict__ R,
                                                    float* __restrict__ w) {
  __shared__ float hs[DM];
  __shared__ float dots[NCMP];
  const int row = blockIdx.x, t = threadIdx.x;
  const float* hr = h + (size_t)row * DM;
  for (int i = t; i < DM; i += 64) hs[i] = hr[i];
  __syncthreads();
  const int o = t >> 2, p = t & 3;
  float acc = 0.f;
  const float* Rp = R + o;
  for (int d = p * 256; d < p * 256 + 256; ++d) acc += hs[d] * Rp[(size_t)d * NCMP];
  acc += __shfl_xor(acc, 1);
  acc += __shfl_xor(acc, 2);
  if (p == 0) dots[o] = acc;
  __syncthreads();
  if (t == 0) {
    float m = dots[0];
    for (int i = 1; i < NCMP; ++i) m = fmaxf(m, dots[i]);
    float sum = 0.f;
    for (int i = 0; i < NCMP; ++i) { float e = expf(dots[i] - m); dots[i] = e; sum += e; }
    const float inv = 1.f / sum;
    for (int i = 0; i < NCMP; ++i) dots[i] *= inv;
  }
  __syncthreads();
  if (t < NCMP) w[(size_t)row * NCMP + t] = dots[t];
}

// ---------------- generic 64x64-tile fp32 GEMM, BK=16, optional residual ----------------
// C[M,N] = A[M,K] @ B + (res ? res : 0).  NEUR=true: B is compress_neurons [16][K][128]
// viewed as a [K, 2048] matrix whose 128-col blocks come from consecutive neurons.
template <bool NEUR>
__global__ __launch_bounds__(256) void gemm64(const float* __restrict__ A,
                                              const float* __restrict__ B,
                                              float* __restrict__ C,
                                              const float* __restrict__ res,
                                              int M, int N, int K) {
  __shared__ float As[64][17];   // [m][k], +1 pad
  __shared__ float Bs[16][64];   // [k][n]
  const int t = threadIdx.x;
  const int tx = t & 15, ty = t >> 4;
  const int row0 = blockIdx.y * 64, col0 = blockIdx.x * 64;
  const float* Bb;
  int bstride;
  if (NEUR) {
    Bb = B + (size_t)(col0 >> 7) * (size_t)K * 128 + (col0 & 127);
    bstride = 128;
  } else {
    Bb = B + col0;
    bstride = N;
  }
  float acc[4][4];
#pragma unroll
  for (int i = 0; i < 4; ++i)
#pragma unroll
    for (int j = 0; j < 4; ++j) acc[i][j] = 0.f;

  for (int k0 = 0; k0 < K; k0 += 16) {
#pragma unroll
    for (int i = 0; i < 4; ++i) {
      const int idx = t + i * 256;
      const int r = idx >> 4, kk = idx & 15;
      As[r][kk] = A[(size_t)(row0 + r) * K + k0 + kk];
    }
#pragma unroll
    for (int i = 0; i < 4; ++i) {
      const int idx = t + i * 256;
      const int kk = idx >> 6, c = idx & 63;
      Bs[kk][c] = Bb[(size_t)(k0 + kk) * bstride + c];
    }
    __syncthreads();
#pragma unroll
    for (int kk = 0; kk < 16; ++kk) {
      float av[4];
#pragma unroll
      for (int i = 0; i < 4; ++i) av[i] = As[ty * 4 + i][kk];
      const float4 b4 = *reinterpret_cast<const float4*>(&Bs[kk][tx * 4]);
      const float bv[4] = {b4.x, b4.y, b4.z, b4.w};
#pragma unroll
      for (int i = 0; i < 4; ++i)
#pragma unroll
        for (int j = 0; j < 4; ++j) acc[i][j] += av[i] * bv[j];
    }
    __syncthreads();
  }
#pragma unroll
  for (int i = 0; i < 4; ++i) {
    const size_t off = (size_t)(row0 + ty * 4 + i) * N + col0 + tx * 4;
    float4 o4;
    o4.x = acc[i][0]; o4.y = acc[i][1]; o4.z = acc[i][2]; o4.w = acc[i][3];
    if (res) {
      const float4 r4 = *reinterpret_cast<const float4*>(&res[off]);
      o4.x += r4.x; o4.y += r4.y; o4.z += r4.z; o4.w += r4.w;
    }
    *reinterpret_cast<float4*>(&C[off]) = o4;
  }
}

// ---------------- weighted sum over experts: o[row][r] = sum_n ap[row][n*128+r]*w[row][n] ----------------
__global__ __launch_bounds__(128) void wsum_kernel(const float* __restrict__ ap,
                                                   const float* __restrict__ w0,
                                                   const float* __restrict__ w1,
                                                   const float* __restrict__ w2,
                                                   float* __restrict__ o0,
                                                   float* __restrict__ o1,
                                                   float* __restrict__ o2,
                                                   float scale) {
  const int row = blockIdx.x, r = threadIdx.x;
  float wa[16], wb[16], wc[16];
#pragma unroll
  for (int n = 0; n < 16; ++n) wa[n] = w0[(size_t)row * NCMP + n];
  if (w1) {
#pragma unroll
    for (int n = 0; n < 16; ++n) wb[n] = w1[(size_t)row * NCMP + n];
  }
  if (w2) {
#pragma unroll
    for (int n = 0; n < 16; ++n) wc[n] = w2[(size_t)row * NCMP + n];
  }
  float a0 = 0.f, a1 = 0.f, a2 = 0.f;
  const float* apr = ap + (size_t)row * (NCMP * RANK) + r;
#pragma unroll
  for (int n = 0; n < 16; ++n) {
    const float v = apr[n * RANK];
    a0 += v * wa[n];
    if (w1) a1 += v * wb[n];
    if (w2) a2 += v * wc[n];
  }
  o0[(size_t)row * RANK + r] = a0 * scale;
  if (o1) o1[(size_t)row * RANK + r] = a1 * scale;
  if (o2) o2[(size_t)row * RANK + r] = a2 * scale;
}

// ---------------- flash attention, causal, d_head=64; block = (q-tile 64) x (b,h) ----------------
// Q/K/V are [4096][1024] with head h at cols h*64..h*64+63. Q pre-scaled by 1/8 on load.
__global__ __launch_bounds__(256) void flash_kernel(const float* __restrict__ Q,
                                                    const float* __restrict__ K,
                                                    const float* __restrict__ V,
                                                    float* __restrict__ O) {
  __shared__ float Qs[64][68];
  __shared__ float KP[64][68];   // K tile, then reused for P tile
  __shared__ float Vs[64][68];
  const int qt = blockIdx.x, bh = blockIdx.y;
  const int b = bh >> 4, hh = bh & 15;
  const int base = b * 1024;
  const int q0 = qt * 64;
  const int t = threadIdx.x, tx = t & 15, ty = t >> 4;
  const int col = hh * 64;
#pragma unroll
  for (int i = 0; i < 16; ++i) {
    const int idx = t + i * 256;
    const int r = idx >> 6, c = idx & 63;
    Qs[r][c] = Q[(size_t)(base + q0 + r) * DM + col + c] * 0.125f;
  }
  float m_r[4], l_r[4], oacc[4][4];
#pragma unroll
  for (int i = 0; i < 4; ++i) {
    m_r[i] = NEG_BIG; l_r[i] = 0.f;
#pragma unroll
    for (int j = 0; j < 4; ++j) oacc[i][j] = 0.f;
  }
  __syncthreads();
  for (int kt = 0; kt <= qt; ++kt) {
    const int k0 = kt * 64;
#pragma unroll
    for (int i = 0; i < 16; ++i) {
      const int idx = t + i * 256;
      const int r = idx >> 6, c = idx & 63;
      const size_t goff = (size_t)(base + k0 + r) * DM + col + c;
      KP[r][c] = K[goff];
      Vs[r][c] = V[goff];
    }
    __syncthreads();
    float s[4][4];
#pragma unroll
    for (int i = 0; i < 4; ++i)
#pragma unroll
      for (int j = 0; j < 4; ++j) s[i][j] = 0.f;
#pragma unroll
    for (int kk = 0; kk < 64; kk += 4) {
      float4 q4[4], k4[4];
#pragma unroll
      for (int i = 0; i < 4; ++i) q4[i] = *reinterpret_cast<const float4*>(&Qs[ty * 4 + i][kk]);
#pragma unroll
      for (int j = 0; j < 4; ++j) k4[j] = *reinterpret_cast<const float4*>(&KP[tx + 16 * j][kk]);
#pragma unroll
      for (int i = 0; i < 4; ++i)
#pragma unroll
        for (int j = 0; j < 4; ++j)
          s[i][j] += q4[i].x * k4[j].x + q4[i].y * k4[j].y + q4[i].z * k4[j].z + q4[i].w * k4[j].w;
    }
    if (kt == qt) {
#pragma unroll
      for (int i = 0; i < 4; ++i)
#pragma unroll
        for (int j = 0; j < 4; ++j)
          if (k0 + tx + 16 * j > q0 + ty * 4 + i) s[i][j] = NEG_BIG;
    }
    float pv[4][4];
#pragma unroll
    for (int i = 0; i < 4; ++i) {
      float mt = fmaxf(fmaxf(s[i][0], s[i][1]), fmaxf(s[i][2], s[i][3]));
      mt = fmaxf(mt, __shfl_xor(mt, 1));
      mt = fmaxf(mt, __shfl_xor(mt, 2));
      mt = fmaxf(mt, __shfl_xor(mt, 4));
      mt = fmaxf(mt, __shfl_xor(mt, 8));
      const float mn = fmaxf(m_r[i], mt);
      const float sc = expf(m_r[i] - mn);
      m_r[i] = mn;
      float rs = 0.f;
#pragma unroll
      for (int j = 0; j < 4; ++j) { pv[i][j] = expf(s[i][j] - mn); rs += pv[i][j]; }
      rs += __shfl_xor(rs, 1);
      rs += __shfl_xor(rs, 2);
      rs += __shfl_xor(rs, 4);
      rs += __shfl_xor(rs, 8);
      l_r[i] = l_r[i] * sc + rs;
#pragma unroll
      for (int j = 0; j < 4; ++j) oacc[i][j] *= sc;
    }
    __syncthreads();           // all S reads of K done before P overwrites KP
#pragma unroll
    for (int i = 0; i < 4; ++i)
#pragma unroll
      for (int j = 0; j < 4; ++j) KP[ty * 4 + i][tx + 16 * j] = pv[i][j];
    __syncthreads();
    for (int k = 0; k < 64; ++k) {
      float pr[4], vr[4];
#pragma unroll
      for (int i = 0; i < 4; ++i) pr[i] = KP[ty * 4 + i][k];
#pragma unroll
      for (int j = 0; j < 4; ++j) vr[j] = Vs[k][tx + 16 * j];
#pragma unroll
      for (int i = 0; i < 4; ++i)
#pragma unroll
        for (int j = 0; j < 4; ++j) oacc[i][j] += pr[i] * vr[j];
    }
    __syncthreads();           // before next tile's loads overwrite KP/Vs
  }
#pragma unroll
  for (int i = 0; i < 4; ++i) {
    const float inv = 1.0f / l_r[i];
#pragma unroll
    for (int j = 0; j < 4; ++j)
      O[(size_t)(base + q0 + ty * 4 + i) * DM + col + tx + 16 * j] = oacc[i][j] * inv;
  }
}

// ---------------- per-lane sorted-desc top8 merge across lanes via bitonic network ----------------
__device__ __forceinline__ void bitonic_merge8(float* s, int* id, int lanemask) {
  float os[8]; int oi[8];
#pragma unroll
  for (int k = 0; k < 8; ++k) {
    os[k] = __shfl_xor(s[k], lanemask);
    oi[k] = __shfl_xor(id[k], lanemask);
  }
  float cs[8]; int ci[8];
#pragma unroll
  for (int k = 0; k < 8; ++k) {     // top-8 of union (bitonic)
    const bool a = s[k] >= os[7 - k];
    cs[k] = a ? s[k] : os[7 - k];
    ci[k] = a ? id[k] : oi[7 - k];
  }
#pragma unroll
  for (int d = 4; d >= 1; d >>= 1) {   // bitonic sort desc
#pragma unroll
    for (int k = 0; k < 8; ++k) {
      if ((k & d) == 0) {
        const bool sw = cs[k] < cs[k + d];
        const float a1 = sw ? cs[k + d] : cs[k];
        const float a2 = sw ? cs[k] : cs[k + d];
        const int b1 = sw ? ci[k + d] : ci[k];
        const int b2 = sw ? ci[k] : ci[k + d];
        cs[k] = a1; cs[k + d] = a2; ci[k] = b1; ci[k + d] = b2;
      }
    }
  }
#pragma unroll
  for (int k = 0; k < 8; ++k) { s[k] = cs[k]; id[k] = ci[k]; }
}

// ---------------- fused kscores GEMM + per-row top-8 ----------------
// block: 64 rows x TK_KEYS keys (one split). Qm pre-scaled by 1/sqrt(128).
__global__ __launch_bounds__(256) void topk_kernel(const float* __restrict__ Qm,
                                                   const float* __restrict__ kK,
                                                   float* __restrict__ tks,
                                                   int* __restrict__ tki) {
  __shared__ float Qs[64][132];
  __shared__ float Ks[64][68];
  const int rb = blockIdx.x;
  const int sp = blockIdx.y;
  const int r0 = rb * 64;
  const int kb0 = sp * TK_KEYS;
  const int t = threadIdx.x, tx = t & 15, ty = t >> 4;
#pragma unroll
  for (int i = 0; i < 8; ++i) {
    const int f = (t + i * 256) * 4;
    const int rr = f >> 7, cc = f & 127;
    *reinterpret_cast<float4*>(&Qs[rr][cc]) =
        *reinterpret_cast<const float4*>(&Qm[(size_t)(r0 + rr) * RANK + cc]);
  }
  float tsv[4][8]; int tiv[4][8];
#pragma unroll
  for (int i = 0; i < 4; ++i)
#pragma unroll
    for (int k = 0; k < 8; ++k) { tsv[i][k] = NEG_BIG; tiv[i][k] = 0; }
  __syncthreads();
  for (int ch = 0; ch < TK_KEYS / 64; ++ch) {
    const float* kb = kK + (size_t)(kb0 + ch * 64) * RANK;
    float acc[4][4];
#pragma unroll
    for (int i = 0; i < 4; ++i)
#pragma unroll
      for (int j = 0; j < 4; ++j) acc[i][j] = 0.f;
#pragma unroll
    for (int half = 0; half < 2; ++half) {
#pragma unroll
      for (int i = 0; i < 4; ++i) {
        const int f = (t + i * 256) * 4;
        const int rr = f >> 6, cc = f & 63;
        *reinterpret_cast<float4*>(&Ks[rr][cc]) =
            *reinterpret_cast<const float4*>(&kb[(size_t)rr * RANK + half * 64 + cc]);
      }
      __syncthreads();
#pragma unroll
      for (int kk = 0; kk < 64; kk += 4) {
        float4 q4[4], k4[4];
#pragma unroll
        for (int i = 0; i < 4; ++i)
          q4[i] = *reinterpret_cast<const float4*>(&Qs[ty * 4 + i][half * 64 + kk]);
#pragma unroll
        for (int j = 0; j < 4; ++j)
          k4[j] = *reinterpret_cast<const float4*>(&Ks[tx + 16 * j][kk]);
#pragma unroll
        for (int i = 0; i < 4; ++i)
#pragma unroll
          for (int j = 0; j < 4; ++j)
            acc[i][j] += q4[i].x * k4[j].x + q4[i].y * k4[j].y + q4[i].z * k4[j].z + q4[i].w * k4[j].w;
      }
      __syncthreads();
    }
#pragma unroll
    for (int i = 0; i < 4; ++i) {
#pragma unroll
      for (int j = 0; j < 4; ++j) {
        const float v = acc[i][j];
        const int id = kb0 + ch * 64 + tx + 16 * j;
        if (v > tsv[i][7]) {     // sorted-desc insert, static indices only
#pragma unroll
          for (int k = 7; k >= 1; --k) {
            const bool keep = tsv[i][k] >= v;
            const bool up = tsv[i][k - 1] >= v;
            const float cand = up ? v : tsv[i][k - 1];
            const int candi = up ? id : tiv[i][k - 1];
            tsv[i][k] = keep ? tsv[i][k] : cand;
            tiv[i][k] = keep ? tiv[i][k] : candi;
          }
          if (tsv[i][0] < v) { tsv[i][0] = v; tiv[i][0] = id; }
        }
      }
    }
  }
#pragma unroll
  for (int i = 0; i < 4; ++i) {
    bitonic_merge8(tsv[i], tiv[i], 1);
    bitonic_merge8(tsv[i], tiv[i], 2);
    bitonic_merge8(tsv[i], tiv[i], 4);
    bitonic_merge8(tsv[i], tiv[i], 8);
  }
  if (tx == 0) {
#pragma unroll
    for (int i = 0; i < 4; ++i) {
      const size_t o = ((size_t)sp * NROWS + r0 + ty * 4 + i) * TOPK;
#pragma unroll
      for (int k = 0; k < 8; ++k) { tks[o + k] = tsv[i][k]; tki[o + k] = tiv[i][k]; }
    }
  }
}

// ---------------- merge splits, softmax top-8, gather knowledge_V, out += mem ----------------
__global__ __launch_bounds__(256) void gather_kernel(const float* __restrict__ tks,
                                                     const int* __restrict__ tki,
                                                     const float* __restrict__ kV,
                                                     float* __restrict__ out) {
  __shared__ float ls[TK_SPLIT * TOPK];
  __shared__ int li[TK_SPLIT * TOPK];
  __shared__ float wsel[TOPK];
  __shared__ int isel[TOPK];
  const int row = blockIdx.x, t = threadIdx.x;
  if (t < TK_SPLIT * TOPK) {
    const int l = t >> 3, k = t & 7;
    ls[t] = tks[((size_t)l * NROWS + row) * TOPK + k];
    li[t] = tki[((size_t)l * NROWS + row) * TOPK + k];
  }
  __syncthreads();
  if (t == 0) {
    int head[TK_SPLIT] = {0, 0, 0, 0, 0, 0, 0, 0};
    float picked[TOPK]; int pid[TOPK];
    for (int k = 0; k < TOPK; ++k) {
      float best = NEG_BIG; int bl = 0;
      for (int l = 0; l < TK_SPLIT; ++l) {
        if (head[l] < TOPK) {
          const float v = ls[l * TOPK + head[l]];
          if (v > best) { best = v; bl = l; }
        }
      }
      picked[k] = best;
      pid[k] = li[bl * TOPK + head[bl]];
      head[bl]++;
    }
    const float m = picked[0];       // sorted desc
    float sum = 0.f;
    float e[TOPK];
    for (int k = 0; k < TOPK; ++k) { e[k] = expf(picked[k] - m); sum += e[k]; }
    const float inv = 1.f / sum;
    for (int k = 0; k < TOPK; ++k) { wsel[k] = e[k] * inv; isel[k] = pid[k]; }
  }
  __syncthreads();
  float4 accv = reinterpret_cast<float4*>(out + (size_t)row * DM)[t];
#pragma unroll
  for (int k = 0; k < TOPK; ++k) {
    const float4 v4 = reinterpret_cast<const float4*>(kV + (size_t)isel[k] * DM)[t];
    const float wk = wsel[k];
    accv.x += wk * v4.x; accv.y += wk * v4.y; accv.z += wk * v4.z; accv.w += wk * v4.w;
  }
  reinterpret_cast<float4*>(out + (size_t)row * DM)[t] = accv;
}

extern "C" void kernel_launch(void* const* d_in, const int* in_sizes, int n_in,
                              void* d_out, int out_size, void* d_ws, size_t ws_size,
                              hipStream_t stream) {
  (void)in_sizes; (void)n_in; (void)out_size; (void)ws_size;
  const float* x    = (const float*)d_in[0];
  // d_in[1] = causal mask — implicit in flash kernel
  const float* neur = (const float*)d_in[2];
  const float* kK   = (const float*)d_in[3];
  const float* kV   = (const float*)d_in[4];
  const float* rQ   = (const float*)d_in[5];
  const float* rK   = (const float*)d_in[6];
  const float* rV   = (const float*)d_in[7];
  const float* rM   = (const float*)d_in[8];
  const float* WQ   = (const float*)d_in[9];
  const float* WK   = (const float*)d_in[10];
  const float* WV   = (const float*)d_in[11];
  const float* WO   = (const float*)d_in[12];
  const float* g1   = (const float*)d_in[13];
  const float* b1   = (const float*)d_in[14];
  const float* g2   = (const float*)d_in[15];
  const float* b2   = (const float*)d_in[16];
  float* out = (float*)d_out;

  float* p = (float*)d_ws;
  float* h    = p; p += (size_t)NROWS * DM;            // h / h2 ; reused as V buffer
  float* ap   = p; p += (size_t)NROWS * (NCMP * RANK); // all_proj ; reused as Q,K buffers
  float* attn = p; p += (size_t)NROWS * DM;
  float* wQw  = p; p += NROWS * NCMP;
  float* wKw  = p; p += NROWS * NCMP;
  float* wVw  = p; p += NROWS * NCMP;
  float* wMw  = p; p += NROWS * NCMP;
  float* hQ   = p; p += NROWS * RANK;
  float* hK   = p; p += NROWS * RANK;
  float* hV   = p; p += NROWS * RANK;
  float* Qm   = p; p += NROWS * RANK;
  float* tks  = p; p += TK_SPLIT * NROWS * TOPK;
  int*   tki  = (int*)p;
  float* Qb = ap;                                   // ap dead after wsum
  float* Kb = ap + (size_t)NROWS * DM;
  float* Vb = h;                                    // h dead after routers/wsum

  // ---- attention half ----
  ln_kernel<<<NROWS, 256, 0, stream>>>(x, g1, b1, h);
  gemm64<true><<<dim3(32, 64), 256, 0, stream>>>(h, neur, ap, nullptr, NROWS, NCMP * RANK, DM);
  router_kernel<<<NROWS, 64, 0, stream>>>(h, rQ, wQw);
  router_kernel<<<NROWS, 64, 0, stream>>>(h, rK, wKw);
  router_kernel<<<NROWS, 64, 0, stream>>>(h, rV, wVw);
  wsum_kernel<<<NROWS, 128, 0, stream>>>(ap, wQw, wKw, wVw, hQ, hK, hV, 1.0f);
  gemm64<false><<<dim3(16, 64), 256, 0, stream>>>(hQ, WQ, Qb, nullptr, NROWS, DM, RANK);
  gemm64<false><<<dim3(16, 64), 256, 0, stream>>>(hK, WK, Kb, nullptr, NROWS, DM, RANK);
  gemm64<false><<<dim3(16, 64), 256, 0, stream>>>(hV, WV, Vb, nullptr, NROWS, DM, RANK);
  flash_kernel<<<dim3(16, 64), 256, 0, stream>>>(Qb, Kb, Vb, attn);
  gemm64<false><<<dim3(16, 64), 256, 0, stream>>>(attn, WO, out, x, NROWS, DM, DM);

  // ---- knowledge-memory half ----
  ln_kernel<<<NROWS, 256, 0, stream>>>(out, g2, b2, h);
  gemm64<true><<<dim3(32, 64), 256, 0, stream>>>(h, neur, ap, nullptr, NROWS, NCMP * RANK, DM);
  router_kernel<<<NROWS, 64, 0, stream>>>(h, rM, wMw);
  wsum_kernel<<<NROWS, 128, 0, stream>>>(ap, wMw, nullptr, nullptr, Qm, nullptr, nullptr,
                                         0.08838834764831845f /* 1/sqrt(128) */);
  topk_kernel<<<dim3(64, TK_SPLIT), 256, 0, stream>>>(Qm, kK, tks, tki);
  gather_kernel<<<NROWS, 256, 0, stream>>>(tks, tki, kV, out);
}

// Round 2
// 2726.305 us; speedup vs baseline: 9.1067x; 9.1067x over previous
//
#include <hip/hip_runtime.h>
#include <math.h>

#define DM     1024
#define RANK   128
#define NCMP   16
#define NKNOW  32768
#define TOPK   8
#define NROWS  4096          // B*S
#define NEG_BIG -3.0e38f
#define TK_SPLIT 8
#define TK_KEYS (NKNOW / TK_SPLIT)   // 4096 keys per split

// ---------------- LayerNorm: one block (256 thr) per row of 1024 ----------------
__global__ __launch_bounds__(256) void ln_kernel(const float* __restrict__ x,
                                                 const float* __restrict__ g,
                                                 const float* __restrict__ b,
                                                 float* __restrict__ o) {
  __shared__ float red1[4], red2[4];
  const int row = blockIdx.x, t = threadIdx.x;
  const float4 v = reinterpret_cast<const float4*>(x + (size_t)row * DM)[t];
  float s = v.x + v.y + v.z + v.w;
#pragma unroll
  for (int m = 1; m <= 32; m <<= 1) s += __shfl_xor(s, m);
  if ((t & 63) == 0) red1[t >> 6] = s;
  __syncthreads();
  const float mu = (red1[0] + red1[1] + red1[2] + red1[3]) * (1.0f / DM);
  const float dx = v.x - mu, dy = v.y - mu, dz = v.z - mu, dw = v.w - mu;
  float ss = dx * dx + dy * dy + dz * dz + dw * dw;
#pragma unroll
  for (int m = 1; m <= 32; m <<= 1) ss += __shfl_xor(ss, m);
  if ((t & 63) == 0) red2[t >> 6] = ss;
  __syncthreads();
  const float var = (red2[0] + red2[1] + red2[2] + red2[3]) * (1.0f / DM);
  const float inv = rsqrtf(var + 1e-5f);
  const float4 g4 = reinterpret_cast<const float4*>(g)[t];
  const float4 b4 = reinterpret_cast<const float4*>(b)[t];
  float4 r;
  r.x = dx * inv * g4.x + b4.x;
  r.y = dy * inv * g4.y + b4.y;
  r.z = dz * inv * g4.z + b4.z;
  r.w = dw * inv * g4.w + b4.w;
  reinterpret_cast<float4*>(o + (size_t)row * DM)[t] = r;
}

// ---------------- Router softmax: w[row][0..15] = softmax(h[row] @ R) ----------------
__global__ __launch_bounds__(64) void router_kernel(const float* __restrict__ h,
                                                    const float* __restrict__ R,
                                                    float* __restrict__ w) {
  __shared__ float hs[DM];
  __shared__ float dots[NCMP];
  const int row = blockIdx.x, t = threadIdx.x;
  const float* hr = h + (size_t)row * DM;
  for (int i = t; i < DM; i += 64) hs[i] = hr[i];
  __syncthreads();
  const int o = t >> 2, p = t & 3;
  float acc = 0.f;
  const float* Rp = R + o;
  for (int d = p * 256; d < p * 256 + 256; ++d) acc += hs[d] * Rp[(size_t)d * NCMP];
  acc += __shfl_xor(acc, 1);
  acc += __shfl_xor(acc, 2);
  if (p == 0) dots[o] = acc;
  __syncthreads();
  if (t == 0) {
    float m = dots[0];
    for (int i = 1; i < NCMP; ++i) m = fmaxf(m, dots[i]);
    float sum = 0.f;
    for (int i = 0; i < NCMP; ++i) { float e = expf(dots[i] - m); dots[i] = e; sum += e; }
    const float inv = 1.f / sum;
    for (int i = 0; i < NCMP; ++i) dots[i] *= inv;
  }
  __syncthreads();
  if (t < NCMP) w[(size_t)row * NCMP + t] = dots[t];
}

// ---------------- generic 64x64-tile fp32 GEMM, BK=16, optional residual ----------------
template <bool NEUR>
__global__ __launch_bounds__(256) void gemm64(const float* __restrict__ A,
                                              const float* __restrict__ B,
                                              float* __restrict__ C,
                                              const float* __restrict__ res,
                                              int M, int N, int K) {
  __shared__ float As[64][17];   // [m][k], +1 pad
  __shared__ float Bs[16][64];   // [k][n]
  const int t = threadIdx.x;
  const int tx = t & 15, ty = t >> 4;
  const int row0 = blockIdx.y * 64, col0 = blockIdx.x * 64;
  const float* Bb;
  int bstride;
  if (NEUR) {
    Bb = B + (size_t)(col0 >> 7) * (size_t)K * 128 + (col0 & 127);
    bstride = 128;
  } else {
    Bb = B + col0;
    bstride = N;
  }
  float acc[4][4];
#pragma unroll
  for (int i = 0; i < 4; ++i)
#pragma unroll
    for (int j = 0; j < 4; ++j) acc[i][j] = 0.f;

  for (int k0 = 0; k0 < K; k0 += 16) {
#pragma unroll
    for (int i = 0; i < 4; ++i) {
      const int idx = t + i * 256;
      const int r = idx >> 4, kk = idx & 15;
      As[r][kk] = A[(size_t)(row0 + r) * K + k0 + kk];
    }
#pragma unroll
    for (int i = 0; i < 4; ++i) {
      const int idx = t + i * 256;
      const int kk = idx >> 6, c = idx & 63;
      Bs[kk][c] = Bb[(size_t)(k0 + kk) * bstride + c];
    }
    __syncthreads();
#pragma unroll
    for (int kk = 0; kk < 16; ++kk) {
      float av[4];
#pragma unroll
      for (int i = 0; i < 4; ++i) av[i] = As[ty * 4 + i][kk];
      const float4 b4 = *reinterpret_cast<const float4*>(&Bs[kk][tx * 4]);
      const float bv[4] = {b4.x, b4.y, b4.z, b4.w};
#pragma unroll
      for (int i = 0; i < 4; ++i)
#pragma unroll
        for (int j = 0; j < 4; ++j) acc[i][j] += av[i] * bv[j];
    }
    __syncthreads();
  }
#pragma unroll
  for (int i = 0; i < 4; ++i) {
    const size_t off = (size_t)(row0 + ty * 4 + i) * N + col0 + tx * 4;
    float4 o4;
    o4.x = acc[i][0]; o4.y = acc[i][1]; o4.z = acc[i][2]; o4.w = acc[i][3];
    if (res) {
      const float4 r4 = *reinterpret_cast<const float4*>(&res[off]);
      o4.x += r4.x; o4.y += r4.y; o4.z += r4.z; o4.w += r4.w;
    }
    *reinterpret_cast<float4*>(&C[off]) = o4;
  }
}

// ---------------- weighted sum over experts ----------------
__global__ __launch_bounds__(128) void wsum_kernel(const float* __restrict__ ap,
                                                   const float* __restrict__ w0,
                                                   const float* __restrict__ w1,
                                                   const float* __restrict__ w2,
                                                   float* __restrict__ o0,
                                                   float* __restrict__ o1,
                                                   float* __restrict__ o2,
                                                   float scale) {
  const int row = blockIdx.x, r = threadIdx.x;
  float wa[16], wb[16], wc[16];
#pragma unroll
  for (int n = 0; n < 16; ++n) wa[n] = w0[(size_t)row * NCMP + n];
  if (w1) {
#pragma unroll
    for (int n = 0; n < 16; ++n) wb[n] = w1[(size_t)row * NCMP + n];
  }
  if (w2) {
#pragma unroll
    for (int n = 0; n < 16; ++n) wc[n] = w2[(size_t)row * NCMP + n];
  }
  float a0 = 0.f, a1 = 0.f, a2 = 0.f;
  const float* apr = ap + (size_t)row * (NCMP * RANK) + r;
#pragma unroll
  for (int n = 0; n < 16; ++n) {
    const float v = apr[n * RANK];
    a0 += v * wa[n];
    if (w1) a1 += v * wb[n];
    if (w2) a2 += v * wc[n];
  }
  o0[(size_t)row * RANK + r] = a0 * scale;
  if (o1) o1[(size_t)row * RANK + r] = a1 * scale;
  if (o2) o2[(size_t)row * RANK + r] = a2 * scale;
}

// ---------------- flash attention, causal, d_head=64 ----------------
__global__ __launch_bounds__(256) void flash_kernel(const float* __restrict__ Q,
                                                    const float* __restrict__ K,
                                                    const float* __restrict__ V,
                                                    float* __restrict__ O) {
  __shared__ float Qs[64][68];
  __shared__ float KP[64][68];   // K tile, then reused for P tile
  __shared__ float Vs[64][68];
  const int qt = blockIdx.x, bh = blockIdx.y;
  const int b = bh >> 4, hh = bh & 15;
  const int base = b * 1024;
  const int q0 = qt * 64;
  const int t = threadIdx.x, tx = t & 15, ty = t >> 4;
  const int col = hh * 64;
#pragma unroll
  for (int i = 0; i < 16; ++i) {
    const int idx = t + i * 256;
    const int r = idx >> 6, c = idx & 63;
    Qs[r][c] = Q[(size_t)(base + q0 + r) * DM + col + c] * 0.125f;
  }
  float m_r[4], l_r[4], oacc[4][4];
#pragma unroll
  for (int i = 0; i < 4; ++i) {
    m_r[i] = NEG_BIG; l_r[i] = 0.f;
#pragma unroll
    for (int j = 0; j < 4; ++j) oacc[i][j] = 0.f;
  }
  __syncthreads();
  for (int kt = 0; kt <= qt; ++kt) {
    const int k0 = kt * 64;
#pragma unroll
    for (int i = 0; i < 16; ++i) {
      const int idx = t + i * 256;
      const int r = idx >> 6, c = idx & 63;
      const size_t goff = (size_t)(base + k0 + r) * DM + col + c;
      KP[r][c] = K[goff];
      Vs[r][c] = V[goff];
    }
    __syncthreads();
    float s[4][4];
#pragma unroll
    for (int i = 0; i < 4; ++i)
#pragma unroll
      for (int j = 0; j < 4; ++j) s[i][j] = 0.f;
#pragma unroll
    for (int kk = 0; kk < 64; kk += 4) {
      float4 q4[4], k4[4];
#pragma unroll
      for (int i = 0; i < 4; ++i) q4[i] = *reinterpret_cast<const float4*>(&Qs[ty * 4 + i][kk]);
#pragma unroll
      for (int j = 0; j < 4; ++j) k4[j] = *reinterpret_cast<const float4*>(&KP[tx + 16 * j][kk]);
#pragma unroll
      for (int i = 0; i < 4; ++i)
#pragma unroll
        for (int j = 0; j < 4; ++j)
          s[i][j] += q4[i].x * k4[j].x + q4[i].y * k4[j].y + q4[i].z * k4[j].z + q4[i].w * k4[j].w;
    }
    if (kt == qt) {
#pragma unroll
      for (int i = 0; i < 4; ++i)
#pragma unroll
        for (int j = 0; j < 4; ++j)
          if (k0 + tx + 16 * j > q0 + ty * 4 + i) s[i][j] = NEG_BIG;
    }
    float pv[4][4];
#pragma unroll
    for (int i = 0; i < 4; ++i) {
      float mt = fmaxf(fmaxf(s[i][0], s[i][1]), fmaxf(s[i][2], s[i][3]));
      mt = fmaxf(mt, __shfl_xor(mt, 1));
      mt = fmaxf(mt, __shfl_xor(mt, 2));
      mt = fmaxf(mt, __shfl_xor(mt, 4));
      mt = fmaxf(mt, __shfl_xor(mt, 8));
      const float mn = fmaxf(m_r[i], mt);
      const float sc = expf(m_r[i] - mn);
      m_r[i] = mn;
      float rs = 0.f;
#pragma unroll
      for (int j = 0; j < 4; ++j) { pv[i][j] = expf(s[i][j] - mn); rs += pv[i][j]; }
      rs += __shfl_xor(rs, 1);
      rs += __shfl_xor(rs, 2);
      rs += __shfl_xor(rs, 4);
      rs += __shfl_xor(rs, 8);
      l_r[i] = l_r[i] * sc + rs;
#pragma unroll
      for (int j = 0; j < 4; ++j) oacc[i][j] *= sc;
    }
    __syncthreads();
#pragma unroll
    for (int i = 0; i < 4; ++i)
#pragma unroll
      for (int j = 0; j < 4; ++j) KP[ty * 4 + i][tx + 16 * j] = pv[i][j];
    __syncthreads();
    for (int k = 0; k < 64; ++k) {
      float pr[4], vr[4];
#pragma unroll
      for (int i = 0; i < 4; ++i) pr[i] = KP[ty * 4 + i][k];
#pragma unroll
      for (int j = 0; j < 4; ++j) vr[j] = Vs[k][tx + 16 * j];
#pragma unroll
      for (int i = 0; i < 4; ++i)
#pragma unroll
        for (int j = 0; j < 4; ++j) oacc[i][j] += pr[i] * vr[j];
    }
    __syncthreads();
  }
#pragma unroll
  for (int i = 0; i < 4; ++i) {
    const float inv = 1.0f / l_r[i];
#pragma unroll
    for (int j = 0; j < 4; ++j)
      O[(size_t)(base + q0 + ty * 4 + i) * DM + col + tx + 16 * j] = oacc[i][j] * inv;
  }
}

// ---------------- fused kscores GEMM + per-row top-8 (spill-free) ----------------
// Block: 64 rows x 4096 keys (one split). GEMM 64x64 score tiles -> LDS ->
// per-thread single top-8 list over one row / 16-key slot -> 4-way merge.
__global__ __launch_bounds__(256) void topk_kernel(const float* __restrict__ Qm,
                                                   const float* __restrict__ kK,
                                                   float* __restrict__ tks,
                                                   int* __restrict__ tki) {
  __shared__ float Qs[64][132];
  __shared__ float Ks[64][68];   // K tile; overlaid as score tile [key*65+row] + merge buffer
  float* const scb = &Ks[0][0];
  const int rb = blockIdx.x;
  const int sp = blockIdx.y;
  const int r0 = rb * 64;
  const int kb0 = sp * TK_KEYS;
  const int t = threadIdx.x, tx = t & 15, ty = t >> 4;
  const int srow = t & 63, slot = t >> 6;
#pragma unroll
  for (int i = 0; i < 8; ++i) {
    const int f = (t + i * 256) * 4;
    const int rr = f >> 7, cc = f & 127;
    *reinterpret_cast<float4*>(&Qs[rr][cc]) =
        *reinterpret_cast<const float4*>(&Qm[(size_t)(r0 + rr) * RANK + cc]);
  }
  float bs[8]; int bi[8];
#pragma unroll
  for (int k = 0; k < 8; ++k) { bs[k] = NEG_BIG; bi[k] = 0; }
  __syncthreads();

  for (int ch = 0; ch < TK_KEYS / 64; ++ch) {
    const float* kb = kK + (size_t)(kb0 + ch * 64) * RANK;
    float acc[4][4];
#pragma unroll
    for (int i = 0; i < 4; ++i)
#pragma unroll
      for (int j = 0; j < 4; ++j) acc[i][j] = 0.f;
#pragma unroll
    for (int half = 0; half < 2; ++half) {
#pragma unroll
      for (int i = 0; i < 4; ++i) {
        const int f = (t + i * 256) * 4;
        const int rr = f >> 6, cc = f & 63;
        *reinterpret_cast<float4*>(&Ks[rr][cc]) =
            *reinterpret_cast<const float4*>(&kb[(size_t)rr * RANK + half * 64 + cc]);
      }
      __syncthreads();
#pragma unroll
      for (int kk = 0; kk < 64; kk += 4) {
        float4 q4[4], k4[4];
#pragma unroll
        for (int i = 0; i < 4; ++i)
          q4[i] = *reinterpret_cast<const float4*>(&Qs[ty * 4 + i][half * 64 + kk]);
#pragma unroll
        for (int j = 0; j < 4; ++j)
          k4[j] = *reinterpret_cast<const float4*>(&Ks[tx + 16 * j][kk]);
#pragma unroll
        for (int i = 0; i < 4; ++i)
#pragma unroll
          for (int j = 0; j < 4; ++j)
            acc[i][j] += q4[i].x * k4[j].x + q4[i].y * k4[j].y + q4[i].z * k4[j].z + q4[i].w * k4[j].w;
      }
      __syncthreads();
    }
    // dump scores: scb[key*65 + row]
#pragma unroll
    for (int i = 0; i < 4; ++i)
#pragma unroll
      for (int j = 0; j < 4; ++j)
        scb[(tx + 16 * j) * 65 + ty * 4 + i] = acc[i][j];
    __syncthreads();
    // selection: thread owns (row srow, keys slot*16..slot*16+15)
    const int idbase = kb0 + ch * 64 + slot * 16;
#pragma unroll
    for (int jj = 0; jj < 16; ++jj) {
      const float v = scb[(slot * 16 + jj) * 65 + srow];
      if (v > bs[7]) {
        const int id = idbase + jj;
#pragma unroll
        for (int k = 7; k >= 1; --k) {
          const bool keep = bs[k] >= v;
          const bool up = bs[k - 1] >= v;
          const float cand = up ? v : bs[k - 1];
          const int candi = up ? id : bi[k - 1];
          bs[k] = keep ? bs[k] : cand;
          bi[k] = keep ? bi[k] : candi;
        }
        if (bs[0] < v) { bs[0] = v; bi[0] = id; }
      }
    }
    __syncthreads();
  }

  // stash per-thread sorted lists: vals at q=slot*8+k, idx at q=32+slot*8+k
#pragma unroll
  for (int k = 0; k < 8; ++k) {
    scb[(slot * 8 + k) * 65 + srow] = bs[k];
    scb[(32 + slot * 8 + k) * 65 + srow] = __int_as_float(bi[k]);
  }
  __syncthreads();
  if (t < 64) {
    const int row = t;
    int h0 = 0, h1 = 0, h2 = 0, h3 = 0;
    const size_t o = ((size_t)sp * NROWS + r0 + row) * TOPK;
    for (int k = 0; k < TOPK; ++k) {
      const float c0 = (h0 < 8) ? scb[(0 + h0) * 65 + row] : NEG_BIG;
      const float c1 = (h1 < 8) ? scb[(8 + h1) * 65 + row] : NEG_BIG;
      const float c2 = (h2 < 8) ? scb[(16 + h2) * 65 + row] : NEG_BIG;
      const float c3 = (h3 < 8) ? scb[(24 + h3) * 65 + row] : NEG_BIG;
      const float m01 = fmaxf(c0, c1); const int l01 = (c0 >= c1) ? 0 : 1;
      const float m23 = fmaxf(c2, c3); const int l23 = (c2 >= c3) ? 2 : 3;
      const float bv = fmaxf(m01, m23);
      const int bl = (m01 >= m23) ? l01 : l23;
      const int hb = (bl == 0) ? h0 : (bl == 1) ? h1 : (bl == 2) ? h2 : h3;
      const int idx = __float_as_int(scb[(32 + bl * 8 + hb) * 65 + row]);
      tks[o + k] = bv;
      tki[o + k] = idx;
      h0 += (bl == 0); h1 += (bl == 1); h2 += (bl == 2); h3 += (bl == 3);
    }
  }
}

// ---------------- merge splits, softmax top-8, gather knowledge_V, out += mem ----------------
__global__ __launch_bounds__(256) void gather_kernel(const float* __restrict__ tks,
                                                     const int* __restrict__ tki,
                                                     const float* __restrict__ kV,
                                                     float* __restrict__ out) {
  __shared__ float ls[TK_SPLIT * TOPK];
  __shared__ int li[TK_SPLIT * TOPK];
  __shared__ float wsel[TOPK];
  __shared__ int isel[TOPK];
  const int row = blockIdx.x, t = threadIdx.x;
  if (t < TK_SPLIT * TOPK) {
    const int l = t >> 3, k = t & 7;
    ls[t] = tks[((size_t)l * NROWS + row) * TOPK + k];
    li[t] = tki[((size_t)l * NROWS + row) * TOPK + k];
  }
  __syncthreads();
  if (t == 0) {
    int head[TK_SPLIT] = {0, 0, 0, 0, 0, 0, 0, 0};
    float picked[TOPK]; int pid[TOPK];
    for (int k = 0; k < TOPK; ++k) {
      float best = NEG_BIG; int bl = 0;
      for (int l = 0; l < TK_SPLIT; ++l) {
        if (head[l] < TOPK) {
          const float v = ls[l * TOPK + head[l]];
          if (v > best) { best = v; bl = l; }
        }
      }
      picked[k] = best;
      pid[k] = li[bl * TOPK + head[bl]];
      head[bl]++;
    }
    const float m = picked[0];
    float sum = 0.f;
    float e[TOPK];
    for (int k = 0; k < TOPK; ++k) { e[k] = expf(picked[k] - m); sum += e[k]; }
    const float inv = 1.f / sum;
    for (int k = 0; k < TOPK; ++k) { wsel[k] = e[k] * inv; isel[k] = pid[k]; }
  }
  __syncthreads();
  float4 accv = reinterpret_cast<float4*>(out + (size_t)row * DM)[t];
#pragma unroll
  for (int k = 0; k < TOPK; ++k) {
    const float4 v4 = reinterpret_cast<const float4*>(kV + (size_t)isel[k] * DM)[t];
    const float wk = wsel[k];
    accv.x += wk * v4.x; accv.y += wk * v4.y; accv.z += wk * v4.z; accv.w += wk * v4.w;
  }
  reinterpret_cast<float4*>(out + (size_t)row * DM)[t] = accv;
}

extern "C" void kernel_launch(void* const* d_in, const int* in_sizes, int n_in,
                              void* d_out, int out_size, void* d_ws, size_t ws_size,
                              hipStream_t stream) {
  (void)in_sizes; (void)n_in; (void)out_size; (void)ws_size;
  const float* x    = (const float*)d_in[0];
  const float* neur = (const float*)d_in[2];
  const float* kK   = (const float*)d_in[3];
  const float* kV   = (const float*)d_in[4];
  const float* rQ   = (const float*)d_in[5];
  const float* rK   = (const float*)d_in[6];
  const float* rV   = (const float*)d_in[7];
  const float* rM   = (const float*)d_in[8];
  const float* WQ   = (const float*)d_in[9];
  const float* WK   = (const float*)d_in[10];
  const float* WV   = (const float*)d_in[11];
  const float* WO   = (const float*)d_in[12];
  const float* g1   = (const float*)d_in[13];
  const float* b1   = (const float*)d_in[14];
  const float* g2   = (const float*)d_in[15];
  const float* b2   = (const float*)d_in[16];
  float* out = (float*)d_out;

  float* p = (float*)d_ws;
  float* h    = p; p += (size_t)NROWS * DM;
  float* ap   = p; p += (size_t)NROWS * (NCMP * RANK);
  float* attn = p; p += (size_t)NROWS * DM;
  float* wQw  = p; p += NROWS * NCMP;
  float* wKw  = p; p += NROWS * NCMP;
  float* wVw  = p; p += NROWS * NCMP;
  float* wMw  = p; p += NROWS * NCMP;
  float* hQ   = p; p += NROWS * RANK;
  float* hK   = p; p += NROWS * RANK;
  float* hV   = p; p += NROWS * RANK;
  float* Qm   = p; p += NROWS * RANK;
  float* tks  = p; p += TK_SPLIT * NROWS * TOPK;
  int*   tki  = (int*)p;
  float* Qb = ap;
  float* Kb = ap + (size_t)NROWS * DM;
  float* Vb = h;

  // ---- attention half ----
  ln_kernel<<<NROWS, 256, 0, stream>>>(x, g1, b1, h);
  gemm64<true><<<dim3(32, 64), 256, 0, stream>>>(h, neur, ap, nullptr, NROWS, NCMP * RANK, DM);
  router_kernel<<<NROWS, 64, 0, stream>>>(h, rQ, wQw);
  router_kernel<<<NROWS, 64, 0, stream>>>(h, rK, wKw);
  router_kernel<<<NROWS, 64, 0, stream>>>(h, rV, wVw);
  wsum_kernel<<<NROWS, 128, 0, stream>>>(ap, wQw, wKw, wVw, hQ, hK, hV, 1.0f);
  gemm64<false><<<dim3(16, 64), 256, 0, stream>>>(hQ, WQ, Qb, nullptr, NROWS, DM, RANK);
  gemm64<false><<<dim3(16, 64), 256, 0, stream>>>(hK, WK, Kb, nullptr, NROWS, DM, RANK);
  gemm64<false><<<dim3(16, 64), 256, 0, stream>>>(hV, WV, Vb, nullptr, NROWS, DM, RANK);
  flash_kernel<<<dim3(16, 64), 256, 0, stream>>>(Qb, Kb, Vb, attn);
  gemm64<false><<<dim3(16, 64), 256, 0, stream>>>(attn, WO, out, x, NROWS, DM, DM);

  // ---- knowledge-memory half ----
  ln_kernel<<<NROWS, 256, 0, stream>>>(out, g2, b2, h);
  gemm64<true><<<dim3(32, 64), 256, 0, stream>>>(h, neur, ap, nullptr, NROWS, NCMP * RANK, DM);
  router_kernel<<<NROWS, 64, 0, stream>>>(h, rM, wMw);
  wsum_kernel<<<NROWS, 128, 0, stream>>>(ap, wMw, nullptr, nullptr, Qm, nullptr, nullptr,
                                         0.08838834764831845f /* 1/sqrt(128) */);
  topk_kernel<<<dim3(64, TK_SPLIT), 256, 0, stream>>>(Qm, kK, tks, tki);
  gather_kernel<<<NROWS, 256, 0, stream>>>(tks, tki, kV, out);
}

// Round 3
// 547.967 us; speedup vs baseline: 45.3084x; 4.9753x over previous
//
#include <hip/hip_runtime.h>
#include <math.h>

#define DM     1024
#define RANK   128
#define NCMP   16
#define NKNOW  32768
#define TOPK   8
#define NROWS  4096          // B*S
#define NEG_BIG -3.0e38f
#define TK_SPLIT 8
#define TK_KEYS (NKNOW / TK_SPLIT)   // 4096 keys per split

typedef __attribute__((ext_vector_type(8))) short s8v;    // 8 bf16 (4 VGPRs)
typedef __attribute__((ext_vector_type(4))) float f4v;    // MFMA acc

__device__ __forceinline__ unsigned short f2bf(float f) {
  union { float fl; unsigned u; } v; v.fl = f;
  return (unsigned short)((v.u + 0x7FFFu + ((v.u >> 16) & 1u)) >> 16);  // RNE
}
__device__ __forceinline__ f4v mfma16(s8v a, s8v b, f4v c) {
  return __builtin_amdgcn_mfma_f32_16x16x32_bf16(a, b, c, 0, 0, 0);
}

// ---------------- LayerNorm: writes fp32 and bf16 copies ----------------
__global__ __launch_bounds__(256) void ln_kernel(const float* __restrict__ x,
                                                 const float* __restrict__ g,
                                                 const float* __restrict__ b,
                                                 float* __restrict__ o,
                                                 unsigned short* __restrict__ obf) {
  __shared__ float red1[4], red2[4];
  const int row = blockIdx.x, t = threadIdx.x;
  const float4 v = reinterpret_cast<const float4*>(x + (size_t)row * DM)[t];
  float s = v.x + v.y + v.z + v.w;
#pragma unroll
  for (int m = 1; m <= 32; m <<= 1) s += __shfl_xor(s, m);
  if ((t & 63) == 0) red1[t >> 6] = s;
  __syncthreads();
  const float mu = (red1[0] + red1[1] + red1[2] + red1[3]) * (1.0f / DM);
  const float dx = v.x - mu, dy = v.y - mu, dz = v.z - mu, dw = v.w - mu;
  float ss = dx * dx + dy * dy + dz * dz + dw * dw;
#pragma unroll
  for (int m = 1; m <= 32; m <<= 1) ss += __shfl_xor(ss, m);
  if ((t & 63) == 0) red2[t >> 6] = ss;
  __syncthreads();
  const float var = (red2[0] + red2[1] + red2[2] + red2[3]) * (1.0f / DM);
  const float inv = rsqrtf(var + 1e-5f);
  const float4 g4 = reinterpret_cast<const float4*>(g)[t];
  const float4 b4 = reinterpret_cast<const float4*>(b)[t];
  float4 r;
  r.x = dx * inv * g4.x + b4.x;
  r.y = dy * inv * g4.y + b4.y;
  r.z = dz * inv * g4.z + b4.z;
  r.w = dw * inv * g4.w + b4.w;
  reinterpret_cast<float4*>(o + (size_t)row * DM)[t] = r;
  ushort4 u = make_ushort4(f2bf(r.x), f2bf(r.y), f2bf(r.z), f2bf(r.w));
  reinterpret_cast<ushort4*>(obf + (size_t)row * DM)[t] = u;
}

// ---------------- batched transpose + bf16 convert: out[b][n][k] = in[b][k][n] ----------------
__global__ __launch_bounds__(256) void tcvt_kernel(const float* __restrict__ in,
                                                   unsigned short* __restrict__ out,
                                                   int K, int N) {
  __shared__ float ld[32][33];
  const int bb = blockIdx.z;
  const int k0 = blockIdx.y * 32, n0 = blockIdx.x * 32;
  const int t = threadIdx.x;
  const float* ib = in + (size_t)bb * K * N;
  unsigned short* ob = out + (size_t)bb * K * N;
  const int kl = t >> 3, nl = (t & 7) * 4;
  const float4 v = *reinterpret_cast<const float4*>(&ib[(size_t)(k0 + kl) * N + n0 + nl]);
  ld[kl][nl] = v.x; ld[kl][nl + 1] = v.y; ld[kl][nl + 2] = v.z; ld[kl][nl + 3] = v.w;
  __syncthreads();
  const int nw = t >> 3, kw = (t & 7) * 4;
  ushort4 o = make_ushort4(f2bf(ld[kw][nw]), f2bf(ld[kw + 1][nw]),
                           f2bf(ld[kw + 2][nw]), f2bf(ld[kw + 3][nw]));
  *reinterpret_cast<ushort4*>(&ob[(size_t)(n0 + nw) * K + k0 + kw]) = o;
}

// ---------------- flat fp32 -> bf16 convert (8 elems/thread) ----------------
__global__ __launch_bounds__(256) void cvt_kernel(const float* __restrict__ in,
                                                  unsigned short* __restrict__ out, int n8) {
  const int i = blockIdx.x * 256 + threadIdx.x;
  if (i < n8) {
    const float4 a = reinterpret_cast<const float4*>(in)[2 * i];
    const float4 b = reinterpret_cast<const float4*>(in)[2 * i + 1];
    reinterpret_cast<ushort4*>(out)[2 * i] =
        make_ushort4(f2bf(a.x), f2bf(a.y), f2bf(a.z), f2bf(a.w));
    reinterpret_cast<ushort4*>(out)[2 * i + 1] =
        make_ushort4(f2bf(b.x), f2bf(b.y), f2bf(b.z), f2bf(b.w));
  }
}

// ---------------- Router softmax, coalesced: 256 thr per row ----------------
__global__ __launch_bounds__(256) void router_kernel(const float* __restrict__ h,
                                                     const float* __restrict__ R,
                                                     float* __restrict__ w) {
  __shared__ float hs[DM];
  __shared__ float red[16][17];
  const int row = blockIdx.x, t = threadIdx.x;
  reinterpret_cast<float4*>(hs)[t] = reinterpret_cast<const float4*>(h + (size_t)row * DM)[t];
  __syncthreads();
  const int o = t & 15, seg = t >> 4;
  float acc = 0.f;
  for (int d = seg * 64; d < seg * 64 + 64; ++d) acc += hs[d] * R[d * NCMP + o];
  red[seg][o] = acc;
  __syncthreads();
  if (t < 16) {
    float dot = 0.f;
#pragma unroll
    for (int s = 0; s < 16; ++s) dot += red[s][t];
    float m = dot;
#pragma unroll
    for (int msk = 1; msk < 16; msk <<= 1) m = fmaxf(m, __shfl_xor(m, msk));
    const float e = __expf(dot - m);
    float ssum = e;
#pragma unroll
    for (int msk = 1; msk < 16; msk <<= 1) ssum += __shfl_xor(ssum, msk);
    w[(size_t)row * NCMP + t] = e / ssum;
  }
}

// ---------------- generic NT MFMA GEMM: C[M,N] = A[M,K] @ B^T (B is [N,K]) ----------------
// 128x128 tile, BK=64, 4 waves (2x2), 16 MFMA frags per wave.
template <bool OUT_BF16, bool RES>
__global__ __launch_bounds__(256) void mfma_nt(const unsigned short* __restrict__ A,
                                               const unsigned short* __restrict__ B,
                                               float* __restrict__ Cf,
                                               unsigned short* __restrict__ Cb,
                                               const float* __restrict__ res,
                                               int M, int N, int K) {
  __shared__ unsigned short As[128 * 72];
  __shared__ unsigned short Bs[128 * 72];
  const int t = threadIdx.x;
  const int lane = t & 63, w = t >> 6;
  const int wm = w >> 1, wn = w & 1;
  const int bm = blockIdx.y, bn = blockIdx.x;
  const int l15 = lane & 15, l4 = lane >> 4;
  f4v acc[4][4] = {};
  const int sr = t >> 1, sh = t & 1;   // staging: 2 threads/row, 64B each
  const unsigned short* ga = A + (size_t)(bm * 128 + sr) * K + sh * 32;
  const unsigned short* gb = B + (size_t)(bn * 128 + sr) * K + sh * 32;
  for (int k0 = 0; k0 < K; k0 += 64) {
#pragma unroll
    for (int j = 0; j < 4; ++j) {
      *reinterpret_cast<s8v*>(&As[sr * 72 + sh * 32 + j * 8]) =
          *reinterpret_cast<const s8v*>(&ga[k0 + j * 8]);
      *reinterpret_cast<s8v*>(&Bs[sr * 72 + sh * 32 + j * 8]) =
          *reinterpret_cast<const s8v*>(&gb[k0 + j * 8]);
    }
    __syncthreads();
#pragma unroll
    for (int ks = 0; ks < 2; ++ks) {
      s8v af[4], bf[4];
#pragma unroll
      for (int i = 0; i < 4; ++i) {
        af[i] = *reinterpret_cast<const s8v*>(&As[(wm * 64 + i * 16 + l15) * 72 + ks * 32 + l4 * 8]);
        bf[i] = *reinterpret_cast<const s8v*>(&Bs[(wn * 64 + i * 16 + l15) * 72 + ks * 32 + l4 * 8]);
      }
#pragma unroll
      for (int i = 0; i < 4; ++i)
#pragma unroll
        for (int j = 0; j < 4; ++j) acc[i][j] = mfma16(af[i], bf[j], acc[i][j]);
    }
    __syncthreads();
  }
#pragma unroll
  for (int i = 0; i < 4; ++i) {
#pragma unroll
    for (int j = 0; j < 4; ++j) {
#pragma unroll
      for (int r = 0; r < 4; ++r) {
        const int row = bm * 128 + wm * 64 + i * 16 + l4 * 4 + r;
        const int col = bn * 128 + wn * 64 + j * 16 + l15;
        float v = acc[i][j][r];
        if constexpr (RES) v += res[(size_t)row * N + col];
        if constexpr (OUT_BF16) Cb[(size_t)row * N + col] = f2bf(v);
        else Cf[(size_t)row * N + col] = v;
      }
    }
  }
}

// ---------------- weighted sum over experts -> bf16 outputs ----------------
__global__ __launch_bounds__(128) void wsum_kernel(const float* __restrict__ ap,
                                                   const float* __restrict__ w0,
                                                   const float* __restrict__ w1,
                                                   const float* __restrict__ w2,
                                                   unsigned short* __restrict__ o0,
                                                   unsigned short* __restrict__ o1,
                                                   unsigned short* __restrict__ o2,
                                                   float scale) {
  const int row = blockIdx.x, r = threadIdx.x;
  float wa[16], wb[16], wc[16];
#pragma unroll
  for (int n = 0; n < 16; ++n) wa[n] = w0[(size_t)row * NCMP + n];
  if (w1) {
#pragma unroll
    for (int n = 0; n < 16; ++n) wb[n] = w1[(size_t)row * NCMP + n];
  }
  if (w2) {
#pragma unroll
    for (int n = 0; n < 16; ++n) wc[n] = w2[(size_t)row * NCMP + n];
  }
  float a0 = 0.f, a1 = 0.f, a2 = 0.f;
  const float* apr = ap + (size_t)row * (NCMP * RANK) + r;
#pragma unroll
  for (int n = 0; n < 16; ++n) {
    const float v = apr[n * RANK];
    a0 += v * wa[n];
    if (w1) a1 += v * wb[n];
    if (w2) a2 += v * wc[n];
  }
  o0[(size_t)row * RANK + r] = f2bf(a0 * scale);
  if (o1) o1[(size_t)row * RANK + r] = f2bf(a1 * scale);
  if (o2) o2[(size_t)row * RANK + r] = f2bf(a2 * scale);
}

// ---------------- flash attention (MFMA), causal, d_head=64 ----------------
// Block 256 thr = 4 waves; wave w owns 16 q-rows. Q/K/V bf16 in, attn bf16 out.
__global__ __launch_bounds__(256) void flash_kernel(const unsigned short* __restrict__ Q,
                                                    const unsigned short* __restrict__ K,
                                                    const unsigned short* __restrict__ V,
                                                    unsigned short* __restrict__ O) {
  __shared__ unsigned short Qs[64 * 72], Ks[64 * 72], Vt[64 * 72], Ps[64 * 72];
  const int qt = blockIdx.x, bh = blockIdx.y;
  const int b = bh >> 4, hh = bh & 15;
  const int base = b * 1024, q0 = qt * 64, col = hh * 64;
  const int t = threadIdx.x;
  const int lane = t & 63, w = t >> 6;
  const int l15 = lane & 15, l4 = lane >> 4;
  const int sr = t >> 1, sh = t & 1;
#pragma unroll
  for (int j = 0; j < 4; ++j)
    *reinterpret_cast<s8v*>(&Qs[sr * 72 + sh * 32 + j * 8]) =
        *reinterpret_cast<const s8v*>(&Q[(size_t)(base + q0 + sr) * DM + col + sh * 32 + j * 8]);
  float m_r[4], l_r[4];
  f4v o[4] = {};
#pragma unroll
  for (int r = 0; r < 4; ++r) { m_r[r] = NEG_BIG; l_r[r] = 0.f; }
  __syncthreads();
  for (int kt = 0; kt <= qt; ++kt) {
    const int k0 = kt * 64;
#pragma unroll
    for (int j = 0; j < 4; ++j)
      *reinterpret_cast<s8v*>(&Ks[sr * 72 + sh * 32 + j * 8]) =
          *reinterpret_cast<const s8v*>(&K[(size_t)(base + k0 + sr) * DM + col + sh * 32 + j * 8]);
    {
      const int vk = t >> 2, vd = (t & 3) * 16;
#pragma unroll
      for (int p = 0; p < 2; ++p) {
        s8v vv = *reinterpret_cast<const s8v*>(&V[(size_t)(base + k0 + vk) * DM + col + vd + p * 8]);
#pragma unroll
        for (int e = 0; e < 8; ++e)
          Vt[(vd + p * 8 + e) * 72 + vk] = ((unsigned short*)&vv)[e];
      }
    }
    __syncthreads();
    f4v s[4] = {};
#pragma unroll
    for (int ks = 0; ks < 2; ++ks) {
      s8v a = *reinterpret_cast<const s8v*>(&Qs[(w * 16 + l15) * 72 + ks * 32 + l4 * 8]);
#pragma unroll
      for (int nj = 0; nj < 4; ++nj) {
        s8v bb = *reinterpret_cast<const s8v*>(&Ks[(nj * 16 + l15) * 72 + ks * 32 + l4 * 8]);
        s[nj] = mfma16(a, bb, s[nj]);
      }
    }
#pragma unroll
    for (int r = 0; r < 4; ++r) {
      const int grow = q0 + w * 16 + l4 * 4 + r;
      float sv[4];
#pragma unroll
      for (int nj = 0; nj < 4; ++nj) {
        const float xx = s[nj][r] * 0.125f;
        const int gcol = k0 + nj * 16 + l15;
        sv[nj] = (gcol <= grow) ? xx : NEG_BIG;
      }
      float mt = fmaxf(fmaxf(sv[0], sv[1]), fmaxf(sv[2], sv[3]));
#pragma unroll
      for (int msk = 1; msk < 16; msk <<= 1) mt = fmaxf(mt, __shfl_xor(mt, msk));
      const float mn = fmaxf(m_r[r], mt);
      const float sc = __expf(m_r[r] - mn);
      m_r[r] = mn;
      float rs = 0.f, pv[4];
#pragma unroll
      for (int nj = 0; nj < 4; ++nj) { pv[nj] = __expf(sv[nj] - mn); rs += pv[nj]; }
#pragma unroll
      for (int msk = 1; msk < 16; msk <<= 1) rs += __shfl_xor(rs, msk);
      l_r[r] = l_r[r] * sc + rs;
#pragma unroll
      for (int nd = 0; nd < 4; ++nd) o[nd][r] *= sc;
#pragma unroll
      for (int nj = 0; nj < 4; ++nj)
        Ps[(w * 16 + l4 * 4 + r) * 72 + nj * 16 + l15] = f2bf(pv[nj]);
    }
#pragma unroll
    for (int ks = 0; ks < 2; ++ks) {
      s8v pa = *reinterpret_cast<const s8v*>(&Ps[(w * 16 + l15) * 72 + ks * 32 + l4 * 8]);
#pragma unroll
      for (int nd = 0; nd < 4; ++nd) {
        s8v vb = *reinterpret_cast<const s8v*>(&Vt[(nd * 16 + l15) * 72 + ks * 32 + l4 * 8]);
        o[nd] = mfma16(pa, vb, o[nd]);
      }
    }
    __syncthreads();
  }
#pragma unroll
  for (int nd = 0; nd < 4; ++nd)
#pragma unroll
    for (int r = 0; r < 4; ++r) {
      const int grow = base + q0 + w * 16 + l4 * 4 + r;
      O[(size_t)grow * DM + col + nd * 16 + l15] = f2bf(o[nd][r] / l_r[r]);
    }
}

// ---------------- fused kscores MFMA GEMM + per-row top-8 (spill-free) ----------------
__global__ __launch_bounds__(256) void topk_kernel(const unsigned short* __restrict__ Qm,
                                                   const unsigned short* __restrict__ kK,
                                                   float* __restrict__ tks,
                                                   int* __restrict__ tki) {
  __shared__ unsigned short Kt[64 * 136];
  __shared__ float scb[64 * 65];
  const int rb = blockIdx.x, sp = blockIdx.y;
  const int r0 = rb * 64, kb0 = sp * TK_KEYS;
  const int t = threadIdx.x;
  const int lane = t & 63, w = t >> 6;
  const int l15 = lane & 15, l4 = lane >> 4;
  const int srow = t & 63, slot = t >> 6;
  s8v af[4];
#pragma unroll
  for (int ks = 0; ks < 4; ++ks)
    af[ks] = *reinterpret_cast<const s8v*>(&Qm[(size_t)(r0 + w * 16 + l15) * RANK + ks * 32 + l4 * 8]);
  float bs[8]; int bi[8];
#pragma unroll
  for (int k = 0; k < 8; ++k) { bs[k] = NEG_BIG; bi[k] = 0; }
  const int sk = t >> 2, shh = (t & 3) * 32;
  for (int ch = 0; ch < TK_KEYS / 64; ++ch) {
    const unsigned short* kb = kK + (size_t)(kb0 + ch * 64) * RANK;
#pragma unroll
    for (int j = 0; j < 4; ++j)
      *reinterpret_cast<s8v*>(&Kt[sk * 136 + shh + j * 8]) =
          *reinterpret_cast<const s8v*>(&kb[(size_t)sk * RANK + shh + j * 8]);
    __syncthreads();
    f4v acc[4] = {};
#pragma unroll
    for (int ks = 0; ks < 4; ++ks) {
#pragma unroll
      for (int nj = 0; nj < 4; ++nj) {
        s8v bb = *reinterpret_cast<const s8v*>(&Kt[(nj * 16 + l15) * 136 + ks * 32 + l4 * 8]);
        acc[nj] = mfma16(af[ks], bb, acc[nj]);
      }
    }
#pragma unroll
    for (int nj = 0; nj < 4; ++nj)
#pragma unroll
      for (int r = 0; r < 4; ++r)
        scb[(nj * 16 + l15) * 65 + w * 16 + l4 * 4 + r] = acc[nj][r];
    __syncthreads();
    const int idbase = kb0 + ch * 64 + slot * 16;
#pragma unroll
    for (int jj = 0; jj < 16; ++jj) {
      const float v = scb[(slot * 16 + jj) * 65 + srow];
      if (v > bs[7]) {
        const int id = idbase + jj;
#pragma unroll
        for (int k = 7; k >= 1; --k) {
          const bool keep = bs[k] >= v;
          const bool up = bs[k - 1] >= v;
          const float cand = up ? v : bs[k - 1];
          const int candi = up ? id : bi[k - 1];
          bs[k] = keep ? bs[k] : cand;
          bi[k] = keep ? bi[k] : candi;
        }
        if (bs[0] < v) { bs[0] = v; bi[0] = id; }
      }
    }
    __syncthreads();
  }
#pragma unroll
  for (int k = 0; k < 8; ++k) {
    scb[(slot * 8 + k) * 65 + srow] = bs[k];
    scb[(32 + slot * 8 + k) * 65 + srow] = __int_as_float(bi[k]);
  }
  __syncthreads();
  if (t < 64) {
    const int row = t;
    int h0 = 0, h1 = 0, h2 = 0, h3 = 0;
    const size_t oo = ((size_t)sp * NROWS + r0 + row) * TOPK;
    for (int k = 0; k < TOPK; ++k) {
      const float c0 = (h0 < 8) ? scb[(0 + h0) * 65 + row] : NEG_BIG;
      const float c1 = (h1 < 8) ? scb[(8 + h1) * 65 + row] : NEG_BIG;
      const float c2 = (h2 < 8) ? scb[(16 + h2) * 65 + row] : NEG_BIG;
      const float c3 = (h3 < 8) ? scb[(24 + h3) * 65 + row] : NEG_BIG;
      const float m01 = fmaxf(c0, c1); const int l01 = (c0 >= c1) ? 0 : 1;
      const float m23 = fmaxf(c2, c3); const int l23 = (c2 >= c3) ? 2 : 3;
      const float bv = fmaxf(m01, m23);
      const int bl = (m01 >= m23) ? l01 : l23;
      const int hb = (bl == 0) ? h0 : (bl == 1) ? h1 : (bl == 2) ? h2 : h3;
      const int idx = __float_as_int(scb[(32 + bl * 8 + hb) * 65 + row]);
      tks[oo + k] = bv;
      tki[oo + k] = idx;
      h0 += (bl == 0); h1 += (bl == 1); h2 += (bl == 2); h3 += (bl == 3);
    }
  }
}

// ---------------- merge splits, softmax top-8, gather knowledge_V, out += mem ----------------
__global__ __launch_bounds__(256) void gather_kernel(const float* __restrict__ tks,
                                                     const int* __restrict__ tki,
                                                     const float* __restrict__ kV,
                                                     float* __restrict__ out) {
  __shared__ float ls[TK_SPLIT * TOPK];
  __shared__ int li[TK_SPLIT * TOPK];
  __shared__ float wsel[TOPK];
  __shared__ int isel[TOPK];
  const int row = blockIdx.x, t = threadIdx.x;
  if (t < TK_SPLIT * TOPK) {
    const int l = t >> 3, k = t & 7;
    ls[t] = tks[((size_t)l * NROWS + row) * TOPK + k];
    li[t] = tki[((size_t)l * NROWS + row) * TOPK + k];
  }
  __syncthreads();
  if (t == 0) {
    int head[TK_SPLIT] = {0, 0, 0, 0, 0, 0, 0, 0};
    float picked[TOPK]; int pid[TOPK];
    for (int k = 0; k < TOPK; ++k) {
      float best = NEG_BIG; int bl = 0;
      for (int l = 0; l < TK_SPLIT; ++l) {
        if (head[l] < TOPK) {
          const float v = ls[l * TOPK + head[l]];
          if (v > best) { best = v; bl = l; }
        }
      }
      picked[k] = best;
      pid[k] = li[bl * TOPK + head[bl]];
      head[bl]++;
    }
    const float m = picked[0];
    float sum = 0.f, e[TOPK];
    for (int k = 0; k < TOPK; ++k) { e[k] = expf(picked[k] - m); sum += e[k]; }
    const float inv = 1.f / sum;
    for (int k = 0; k < TOPK; ++k) { wsel[k] = e[k] * inv; isel[k] = pid[k]; }
  }
  __syncthreads();
  float4 accv = reinterpret_cast<float4*>(out + (size_t)row * DM)[t];
#pragma unroll
  for (int k = 0; k < TOPK; ++k) {
    const float4 v4 = reinterpret_cast<const float4*>(kV + (size_t)isel[k] * DM)[t];
    const float wk = wsel[k];
    accv.x += wk * v4.x; accv.y += wk * v4.y; accv.z += wk * v4.z; accv.w += wk * v4.w;
  }
  reinterpret_cast<float4*>(out + (size_t)row * DM)[t] = accv;
}

extern "C" void kernel_launch(void* const* d_in, const int* in_sizes, int n_in,
                              void* d_out, int out_size, void* d_ws, size_t ws_size,
                              hipStream_t stream) {
  (void)in_sizes; (void)n_in; (void)out_size; (void)ws_size;
  const float* x    = (const float*)d_in[0];
  const float* neur = (const float*)d_in[2];
  const float* kK   = (const float*)d_in[3];
  const float* kV   = (const float*)d_in[4];
  const float* rQ   = (const float*)d_in[5];
  const float* rK   = (const float*)d_in[6];
  const float* rV   = (const float*)d_in[7];
  const float* rM   = (const float*)d_in[8];
  const float* WQ   = (const float*)d_in[9];
  const float* WK   = (const float*)d_in[10];
  const float* WV   = (const float*)d_in[11];
  const float* WO   = (const float*)d_in[12];
  const float* g1   = (const float*)d_in[13];
  const float* b1   = (const float*)d_in[14];
  const float* g2   = (const float*)d_in[15];
  const float* b2   = (const float*)d_in[16];
  float* out = (float*)d_out;

  char* base = (char*)d_ws;
  auto alloc = [&](size_t bytes) { char* r = base; base += (bytes + 255) & ~(size_t)255; return r; };
  float*          h     = (float*)alloc((size_t)NROWS * DM * 4);
  unsigned short* hbf   = (unsigned short*)alloc((size_t)NROWS * DM * 2);  // reused as attn_bf
  float*          ap    = (float*)alloc((size_t)NROWS * NCMP * RANK * 4);  // reused as Q/K/V bf16
  unsigned short* neurT = (unsigned short*)alloc((size_t)NCMP * RANK * DM * 2);
  unsigned short* WQt   = (unsigned short*)alloc((size_t)DM * RANK * 2);
  unsigned short* WKt   = (unsigned short*)alloc((size_t)DM * RANK * 2);
  unsigned short* WVt   = (unsigned short*)alloc((size_t)DM * RANK * 2);
  unsigned short* WOt   = (unsigned short*)alloc((size_t)DM * DM * 2);
  unsigned short* kKb   = (unsigned short*)alloc((size_t)NKNOW * RANK * 2);
  unsigned short* hQb   = (unsigned short*)alloc((size_t)NROWS * RANK * 2);
  unsigned short* hKb   = (unsigned short*)alloc((size_t)NROWS * RANK * 2);
  unsigned short* hVb   = (unsigned short*)alloc((size_t)NROWS * RANK * 2);
  unsigned short* Qmb   = (unsigned short*)alloc((size_t)NROWS * RANK * 2);
  float* wQw = (float*)alloc((size_t)NROWS * NCMP * 4);
  float* wKw = (float*)alloc((size_t)NROWS * NCMP * 4);
  float* wVw = (float*)alloc((size_t)NROWS * NCMP * 4);
  float* wMw = (float*)alloc((size_t)NROWS * NCMP * 4);
  float* tks = (float*)alloc((size_t)TK_SPLIT * NROWS * TOPK * 4);
  int*   tki = (int*)alloc((size_t)TK_SPLIT * NROWS * TOPK * 4);
  unsigned short* Qb = (unsigned short*)ap;
  unsigned short* Kb = Qb + (size_t)NROWS * DM;
  unsigned short* Vb = Kb + (size_t)NROWS * DM;
  unsigned short* attnb = hbf;

  // one-time weight converts
  cvt_kernel<<<(NKNOW * RANK / 8 + 255) / 256, 256, 0, stream>>>(kK, kKb, NKNOW * RANK / 8);
  tcvt_kernel<<<dim3(RANK / 32, DM / 32, NCMP), 256, 0, stream>>>(neur, neurT, DM, RANK);
  tcvt_kernel<<<dim3(DM / 32, RANK / 32, 1), 256, 0, stream>>>(WQ, WQt, RANK, DM);
  tcvt_kernel<<<dim3(DM / 32, RANK / 32, 1), 256, 0, stream>>>(WK, WKt, RANK, DM);
  tcvt_kernel<<<dim3(DM / 32, RANK / 32, 1), 256, 0, stream>>>(WV, WVt, RANK, DM);
  tcvt_kernel<<<dim3(DM / 32, DM / 32, 1), 256, 0, stream>>>(WO, WOt, DM, DM);

  // ---- attention half ----
  ln_kernel<<<NROWS, 256, 0, stream>>>(x, g1, b1, h, hbf);
  mfma_nt<false, false><<<dim3(16, 32), 256, 0, stream>>>(hbf, neurT, ap, nullptr, nullptr,
                                                          NROWS, NCMP * RANK, DM);
  router_kernel<<<NROWS, 256, 0, stream>>>(h, rQ, wQw);
  router_kernel<<<NROWS, 256, 0, stream>>>(h, rK, wKw);
  router_kernel<<<NROWS, 256, 0, stream>>>(h, rV, wVw);
  wsum_kernel<<<NROWS, 128, 0, stream>>>(ap, wQw, wKw, wVw, hQb, hKb, hVb, 1.0f);
  mfma_nt<true, false><<<dim3(8, 32), 256, 0, stream>>>(hQb, WQt, nullptr, Qb, nullptr,
                                                        NROWS, DM, RANK);
  mfma_nt<true, false><<<dim3(8, 32), 256, 0, stream>>>(hKb, WKt, nullptr, Kb, nullptr,
                                                        NROWS, DM, RANK);
  mfma_nt<true, false><<<dim3(8, 32), 256, 0, stream>>>(hVb, WVt, nullptr, Vb, nullptr,
                                                        NROWS, DM, RANK);
  flash_kernel<<<dim3(16, 64), 256, 0, stream>>>(Qb, Kb, Vb, attnb);
  mfma_nt<false, true><<<dim3(8, 32), 256, 0, stream>>>(attnb, WOt, out, nullptr, x,
                                                        NROWS, DM, DM);

  // ---- knowledge-memory half ----
  ln_kernel<<<NROWS, 256, 0, stream>>>(out, g2, b2, h, hbf);
  mfma_nt<false, false><<<dim3(16, 32), 256, 0, stream>>>(hbf, neurT, ap, nullptr, nullptr,
                                                          NROWS, NCMP * RANK, DM);
  router_kernel<<<NROWS, 256, 0, stream>>>(h, rM, wMw);
  wsum_kernel<<<NROWS, 128, 0, stream>>>(ap, wMw, nullptr, nullptr, Qmb, nullptr, nullptr,
                                         0.08838834764831845f /* 1/sqrt(128) */);
  topk_kernel<<<dim3(64, TK_SPLIT), 256, 0, stream>>>(Qmb, kKb, tks, tki);
  gather_kernel<<<NROWS, 256, 0, stream>>>(tks, tki, kV, out);
}

// Round 4
// 457.758 us; speedup vs baseline: 54.2372x; 1.1971x over previous
//
#include <hip/hip_runtime.h>
#include <math.h>

#define DM     1024
#define RANK   128
#define NCMP   16
#define NKNOW  32768
#define TOPK   8
#define NROWS  4096          // B*S
#define NEG_BIG -3.0e38f
#define TK_SPLIT 16
#define TK_KEYS (NKNOW / TK_SPLIT)   // 2048 keys per split

typedef __attribute__((ext_vector_type(8))) short s8v;    // 8 bf16 (4 VGPRs)
typedef __attribute__((ext_vector_type(4))) float f4v;    // MFMA acc

__device__ __forceinline__ unsigned short f2bf(float f) {
  union { float fl; unsigned u; } v; v.fl = f;
  return (unsigned short)((v.u + 0x7FFFu + ((v.u >> 16) & 1u)) >> 16);  // RNE
}
__device__ __forceinline__ f4v mfma16(s8v a, s8v b, f4v c) {
  return __builtin_amdgcn_mfma_f32_16x16x32_bf16(a, b, c, 0, 0, 0);
}

// ---------------- LayerNorm: writes fp32 and bf16 copies ----------------
__global__ __launch_bounds__(256) void ln_kernel(const float* __restrict__ x,
                                                 const float* __restrict__ g,
                                                 const float* __restrict__ b,
                                                 float* __restrict__ o,
                                                 unsigned short* __restrict__ obf) {
  __shared__ float red1[4], red2[4];
  const int row = blockIdx.x, t = threadIdx.x;
  const float4 v = reinterpret_cast<const float4*>(x + (size_t)row * DM)[t];
  float s = v.x + v.y + v.z + v.w;
#pragma unroll
  for (int m = 1; m <= 32; m <<= 1) s += __shfl_xor(s, m);
  if ((t & 63) == 0) red1[t >> 6] = s;
  __syncthreads();
  const float mu = (red1[0] + red1[1] + red1[2] + red1[3]) * (1.0f / DM);
  const float dx = v.x - mu, dy = v.y - mu, dz = v.z - mu, dw = v.w - mu;
  float ss = dx * dx + dy * dy + dz * dz + dw * dw;
#pragma unroll
  for (int m = 1; m <= 32; m <<= 1) ss += __shfl_xor(ss, m);
  if ((t & 63) == 0) red2[t >> 6] = ss;
  __syncthreads();
  const float var = (red2[0] + red2[1] + red2[2] + red2[3]) * (1.0f / DM);
  const float inv = rsqrtf(var + 1e-5f);
  const float4 g4 = reinterpret_cast<const float4*>(g)[t];
  const float4 b4 = reinterpret_cast<const float4*>(b)[t];
  float4 r;
  r.x = dx * inv * g4.x + b4.x;
  r.y = dy * inv * g4.y + b4.y;
  r.z = dz * inv * g4.z + b4.z;
  r.w = dw * inv * g4.w + b4.w;
  reinterpret_cast<float4*>(o + (size_t)row * DM)[t] = r;
  ushort4 u = make_ushort4(f2bf(r.x), f2bf(r.y), f2bf(r.z), f2bf(r.w));
  reinterpret_cast<ushort4*>(obf + (size_t)row * DM)[t] = u;
}

// ---------------- batched transpose + bf16 convert: out[b][n][k] = in[b][k][n] ----------------
__global__ __launch_bounds__(256) void tcvt_kernel(const float* __restrict__ in,
                                                   unsigned short* __restrict__ out,
                                                   int K, int N) {
  __shared__ float ld[32][33];
  const int bb = blockIdx.z;
  const int k0 = blockIdx.y * 32, n0 = blockIdx.x * 32;
  const int t = threadIdx.x;
  const float* ib = in + (size_t)bb * K * N;
  unsigned short* ob = out + (size_t)bb * K * N;
  const int kl = t >> 3, nl = (t & 7) * 4;
  const float4 v = *reinterpret_cast<const float4*>(&ib[(size_t)(k0 + kl) * N + n0 + nl]);
  ld[kl][nl] = v.x; ld[kl][nl + 1] = v.y; ld[kl][nl + 2] = v.z; ld[kl][nl + 3] = v.w;
  __syncthreads();
  const int nw = t >> 3, kw = (t & 7) * 4;
  ushort4 o = make_ushort4(f2bf(ld[kw][nw]), f2bf(ld[kw + 1][nw]),
                           f2bf(ld[kw + 2][nw]), f2bf(ld[kw + 3][nw]));
  *reinterpret_cast<ushort4*>(&ob[(size_t)(n0 + nw) * K + k0 + kw]) = o;
}

// ---------------- flat fp32 -> bf16 convert (8 elems/thread) ----------------
__global__ __launch_bounds__(256) void cvt_kernel(const float* __restrict__ in,
                                                  unsigned short* __restrict__ out, int n8) {
  const int i = blockIdx.x * 256 + threadIdx.x;
  if (i < n8) {
    const float4 a = reinterpret_cast<const float4*>(in)[2 * i];
    const float4 b = reinterpret_cast<const float4*>(in)[2 * i + 1];
    reinterpret_cast<ushort4*>(out)[2 * i] =
        make_ushort4(f2bf(a.x), f2bf(a.y), f2bf(a.z), f2bf(a.w));
    reinterpret_cast<ushort4*>(out)[2 * i + 1] =
        make_ushort4(f2bf(b.x), f2bf(b.y), f2bf(b.z), f2bf(b.w));
  }
}

// ---------------- triple router softmax: one block per row, 3 router matrices ----------------
__global__ __launch_bounds__(256) void router3_kernel(const float* __restrict__ h,
                                                      const float* __restrict__ R0,
                                                      const float* __restrict__ R1,
                                                      const float* __restrict__ R2,
                                                      float* __restrict__ w0,
                                                      float* __restrict__ w1,
                                                      float* __restrict__ w2) {
  __shared__ float hs[DM];
  __shared__ float red[3][16][17];
  const int row = blockIdx.x, t = threadIdx.x;
  reinterpret_cast<float4*>(hs)[t] = reinterpret_cast<const float4*>(h + (size_t)row * DM)[t];
  __syncthreads();
  const int o = t & 15, seg = t >> 4;
  float a0 = 0.f, a1 = 0.f, a2 = 0.f;
  for (int d = seg * 64; d < seg * 64 + 64; ++d) {
    const float hv = hs[d];
    a0 += hv * R0[d * NCMP + o];
    a1 += hv * R1[d * NCMP + o];
    a2 += hv * R2[d * NCMP + o];
  }
  red[0][seg][o] = a0; red[1][seg][o] = a1; red[2][seg][o] = a2;
  __syncthreads();
  if (t < 48) {
    const int g = t >> 4, oo = t & 15;
    float dot = 0.f;
#pragma unroll
    for (int s = 0; s < 16; ++s) dot += red[g][s][oo];
    float m = dot;
#pragma unroll
    for (int msk = 1; msk < 16; msk <<= 1) m = fmaxf(m, __shfl_xor(m, msk));
    const float e = __expf(dot - m);
    float ssum = e;
#pragma unroll
    for (int msk = 1; msk < 16; msk <<= 1) ssum += __shfl_xor(ssum, msk);
    float* wp = (g == 0) ? w0 : (g == 1) ? w1 : w2;
    wp[(size_t)row * NCMP + oo] = e / ssum;
  }
}

// ---------------- single router softmax (for rM) ----------------
__global__ __launch_bounds__(256) void router_kernel(const float* __restrict__ h,
                                                     const float* __restrict__ R,
                                                     float* __restrict__ w) {
  __shared__ float hs[DM];
  __shared__ float red[16][17];
  const int row = blockIdx.x, t = threadIdx.x;
  reinterpret_cast<float4*>(hs)[t] = reinterpret_cast<const float4*>(h + (size_t)row * DM)[t];
  __syncthreads();
  const int o = t & 15, seg = t >> 4;
  float acc = 0.f;
  for (int d = seg * 64; d < seg * 64 + 64; ++d) acc += hs[d] * R[d * NCMP + o];
  red[seg][o] = acc;
  __syncthreads();
  if (t < 16) {
    float dot = 0.f;
#pragma unroll
    for (int s = 0; s < 16; ++s) dot += red[s][t];
    float m = dot;
#pragma unroll
    for (int msk = 1; msk < 16; msk <<= 1) m = fmaxf(m, __shfl_xor(m, msk));
    const float e = __expf(dot - m);
    float ssum = e;
#pragma unroll
    for (int msk = 1; msk < 16; msk <<= 1) ssum += __shfl_xor(ssum, msk);
    w[(size_t)row * NCMP + t] = e / ssum;
  }
}

// ---------------- generic NT MFMA GEMM: C[M,N] = A[M,K] @ B^T (B is [N,K]) ----------------
template <bool OUT_BF16, bool RES>
__global__ __launch_bounds__(256) void mfma_nt(const unsigned short* __restrict__ A,
                                               const unsigned short* __restrict__ B,
                                               float* __restrict__ Cf,
                                               unsigned short* __restrict__ Cb,
                                               const float* __restrict__ res,
                                               int M, int N, int K) {
  __shared__ unsigned short As[128 * 72];
  __shared__ unsigned short Bs[128 * 72];
  const int t = threadIdx.x;
  const int lane = t & 63, w = t >> 6;
  const int wm = w >> 1, wn = w & 1;
  const int bm = blockIdx.y, bn = blockIdx.x;
  const int l15 = lane & 15, l4 = lane >> 4;
  f4v acc[4][4] = {};
  const int sr = t >> 1, sh = t & 1;   // staging: 2 threads/row, 64B each
  const unsigned short* ga = A + (size_t)(bm * 128 + sr) * K + sh * 32;
  const unsigned short* gb = B + (size_t)(bn * 128 + sr) * K + sh * 32;
  for (int k0 = 0; k0 < K; k0 += 64) {
#pragma unroll
    for (int j = 0; j < 4; ++j) {
      *reinterpret_cast<s8v*>(&As[sr * 72 + sh * 32 + j * 8]) =
          *reinterpret_cast<const s8v*>(&ga[k0 + j * 8]);
      *reinterpret_cast<s8v*>(&Bs[sr * 72 + sh * 32 + j * 8]) =
          *reinterpret_cast<const s8v*>(&gb[k0 + j * 8]);
    }
    __syncthreads();
#pragma unroll
    for (int ks = 0; ks < 2; ++ks) {
      s8v af[4], bf[4];
#pragma unroll
      for (int i = 0; i < 4; ++i) {
        af[i] = *reinterpret_cast<const s8v*>(&As[(wm * 64 + i * 16 + l15) * 72 + ks * 32 + l4 * 8]);
        bf[i] = *reinterpret_cast<const s8v*>(&Bs[(wn * 64 + i * 16 + l15) * 72 + ks * 32 + l4 * 8]);
      }
#pragma unroll
      for (int i = 0; i < 4; ++i)
#pragma unroll
        for (int j = 0; j < 4; ++j) acc[i][j] = mfma16(af[i], bf[j], acc[i][j]);
    }
    __syncthreads();
  }
#pragma unroll
  for (int i = 0; i < 4; ++i) {
#pragma unroll
    for (int j = 0; j < 4; ++j) {
#pragma unroll
      for (int r = 0; r < 4; ++r) {
        const int row = bm * 128 + wm * 64 + i * 16 + l4 * 4 + r;
        const int col = bn * 128 + wn * 64 + j * 16 + l15;
        float v = acc[i][j][r];
        if constexpr (RES) v += res[(size_t)row * N + col];
        if constexpr (OUT_BF16) Cb[(size_t)row * N + col] = f2bf(v);
        else Cf[(size_t)row * N + col] = v;
      }
    }
  }
}

// ---------------- weighted sum over experts -> bf16 outputs ----------------
__global__ __launch_bounds__(128) void wsum_kernel(const float* __restrict__ ap,
                                                   const float* __restrict__ w0,
                                                   const float* __restrict__ w1,
                                                   const float* __restrict__ w2,
                                                   unsigned short* __restrict__ o0,
                                                   unsigned short* __restrict__ o1,
                                                   unsigned short* __restrict__ o2,
                                                   float scale) {
  const int row = blockIdx.x, r = threadIdx.x;
  float wa[16], wb[16], wc[16];
#pragma unroll
  for (int n = 0; n < 16; ++n) wa[n] = w0[(size_t)row * NCMP + n];
  if (w1) {
#pragma unroll
    for (int n = 0; n < 16; ++n) wb[n] = w1[(size_t)row * NCMP + n];
  }
  if (w2) {
#pragma unroll
    for (int n = 0; n < 16; ++n) wc[n] = w2[(size_t)row * NCMP + n];
  }
  float a0 = 0.f, a1 = 0.f, a2 = 0.f;
  const float* apr = ap + (size_t)row * (NCMP * RANK) + r;
#pragma unroll
  for (int n = 0; n < 16; ++n) {
    const float v = apr[n * RANK];
    a0 += v * wa[n];
    if (w1) a1 += v * wb[n];
    if (w2) a2 += v * wc[n];
  }
  o0[(size_t)row * RANK + r] = f2bf(a0 * scale);
  if (o1) o1[(size_t)row * RANK + r] = f2bf(a1 * scale);
  if (o2) o2[(size_t)row * RANK + r] = f2bf(a2 * scale);
}

// ---------------- flash attention (MFMA), causal, d_head=64 ----------------
__global__ __launch_bounds__(256) void flash_kernel(const unsigned short* __restrict__ Q,
                                                    const unsigned short* __restrict__ K,
                                                    const unsigned short* __restrict__ V,
                                                    unsigned short* __restrict__ O) {
  __shared__ unsigned short Qs[64 * 72], Ks[64 * 72], Vt[64 * 72], Ps[64 * 72];
  const int qt = blockIdx.x, bh = blockIdx.y;
  const int b = bh >> 4, hh = bh & 15;
  const int base = b * 1024, q0 = qt * 64, col = hh * 64;
  const int t = threadIdx.x;
  const int lane = t & 63, w = t >> 6;
  const int l15 = lane & 15, l4 = lane >> 4;
  const int sr = t >> 1, sh = t & 1;
#pragma unroll
  for (int j = 0; j < 4; ++j)
    *reinterpret_cast<s8v*>(&Qs[sr * 72 + sh * 32 + j * 8]) =
        *reinterpret_cast<const s8v*>(&Q[(size_t)(base + q0 + sr) * DM + col + sh * 32 + j * 8]);
  float m_r[4], l_r[4];
  f4v o[4] = {};
#pragma unroll
  for (int r = 0; r < 4; ++r) { m_r[r] = NEG_BIG; l_r[r] = 0.f; }
  __syncthreads();
  for (int kt = 0; kt <= qt; ++kt) {
    const int k0 = kt * 64;
#pragma unroll
    for (int j = 0; j < 4; ++j)
      *reinterpret_cast<s8v*>(&Ks[sr * 72 + sh * 32 + j * 8]) =
          *reinterpret_cast<const s8v*>(&K[(size_t)(base + k0 + sr) * DM + col + sh * 32 + j * 8]);
    {
      const int vk = t >> 2, vd = (t & 3) * 16;
#pragma unroll
      for (int p = 0; p < 2; ++p) {
        s8v vv = *reinterpret_cast<const s8v*>(&V[(size_t)(base + k0 + vk) * DM + col + vd + p * 8]);
#pragma unroll
        for (int e = 0; e < 8; ++e)
          Vt[(vd + p * 8 + e) * 72 + vk] = ((unsigned short*)&vv)[e];
      }
    }
    __syncthreads();
    f4v s[4] = {};
#pragma unroll
    for (int ks = 0; ks < 2; ++ks) {
      s8v a = *reinterpret_cast<const s8v*>(&Qs[(w * 16 + l15) * 72 + ks * 32 + l4 * 8]);
#pragma unroll
      for (int nj = 0; nj < 4; ++nj) {
        s8v bb = *reinterpret_cast<const s8v*>(&Ks[(nj * 16 + l15) * 72 + ks * 32 + l4 * 8]);
        s[nj] = mfma16(a, bb, s[nj]);
      }
    }
#pragma unroll
    for (int r = 0; r < 4; ++r) {
      const int grow = q0 + w * 16 + l4 * 4 + r;
      float sv[4];
#pragma unroll
      for (int nj = 0; nj < 4; ++nj) {
        const float xx = s[nj][r] * 0.125f;
        const int gcol = k0 + nj * 16 + l15;
        sv[nj] = (gcol <= grow) ? xx : NEG_BIG;
      }
      float mt = fmaxf(fmaxf(sv[0], sv[1]), fmaxf(sv[2], sv[3]));
#pragma unroll
      for (int msk = 1; msk < 16; msk <<= 1) mt = fmaxf(mt, __shfl_xor(mt, msk));
      const float mn = fmaxf(m_r[r], mt);
      const float sc = __expf(m_r[r] - mn);
      m_r[r] = mn;
      float rs = 0.f, pv[4];
#pragma unroll
      for (int nj = 0; nj < 4; ++nj) { pv[nj] = __expf(sv[nj] - mn); rs += pv[nj]; }
#pragma unroll
      for (int msk = 1; msk < 16; msk <<= 1) rs += __shfl_xor(rs, msk);
      l_r[r] = l_r[r] * sc + rs;
#pragma unroll
      for (int nd = 0; nd < 4; ++nd) o[nd][r] *= sc;
#pragma unroll
      for (int nj = 0; nj < 4; ++nj)
        Ps[(w * 16 + l4 * 4 + r) * 72 + nj * 16 + l15] = f2bf(pv[nj]);
    }
#pragma unroll
    for (int ks = 0; ks < 2; ++ks) {
      s8v pa = *reinterpret_cast<const s8v*>(&Ps[(w * 16 + l15) * 72 + ks * 32 + l4 * 8]);
#pragma unroll
      for (int nd = 0; nd < 4; ++nd) {
        s8v vb = *reinterpret_cast<const s8v*>(&Vt[(nd * 16 + l15) * 72 + ks * 32 + l4 * 8]);
        o[nd] = mfma16(pa, vb, o[nd]);
      }
    }
    __syncthreads();
  }
#pragma unroll
  for (int nd = 0; nd < 4; ++nd)
#pragma unroll
    for (int r = 0; r < 4; ++r) {
      const int grow = base + q0 + w * 16 + l4 * 4 + r;
      O[(size_t)grow * DM + col + nd * 16 + l15] = f2bf(o[nd][r] / l_r[r]);
    }
}

// ---------------- fused kscores MFMA GEMM + in-register per-row top-8 ----------------
// Swapped operands: mfma(K_frag, Qm_frag) -> S^T, so each lane holds 16 scores of ONE
// row per 64-key chunk; top-8 selection fully in registers. Double-buffered K staging.
__global__ __launch_bounds__(256) void topk_kernel(const unsigned short* __restrict__ Qm,
                                                   const unsigned short* __restrict__ kK,
                                                   float* __restrict__ tks,
                                                   int* __restrict__ tki) {
  __shared__ __align__(16) char arena[2 * 64 * 136 * 2];   // 2 x 17408B K-chunk buffers
  unsigned short* const Kt0 = (unsigned short*)arena;
  unsigned short* const Kt1 = (unsigned short*)(arena + 64 * 136 * 2);
  const int rb = blockIdx.x, sp = blockIdx.y;
  const int r0 = rb * 64, kb0 = sp * TK_KEYS;
  const int t = threadIdx.x;
  const int lane = t & 63, w = t >> 6;
  const int l15 = lane & 15, l4 = lane >> 4;
  // Qm fragments (B operand) for this wave's 16 rows
  s8v qf[4];
#pragma unroll
  for (int ks = 0; ks < 4; ++ks)
    qf[ks] = *reinterpret_cast<const s8v*>(
        &Qm[(size_t)(r0 + w * 16 + l15) * RANK + ks * 32 + l4 * 8]);
  float bs[8]; int bi[8];
#pragma unroll
  for (int k = 0; k < 8; ++k) { bs[k] = NEG_BIG; bi[k] = 0; }
  // staging: thread owns key sk, 64B slot sslot
  const int sk = t >> 2, sslot = t & 3;
  const unsigned short* gk = kK + (size_t)(kb0 + sk) * RANK + sslot * 32;
  const int NCH = TK_KEYS / 64;
  s8v st[4];
#pragma unroll
  for (int j = 0; j < 4; ++j) st[j] = *reinterpret_cast<const s8v*>(&gk[j * 8]);
#pragma unroll
  for (int j = 0; j < 4; ++j)
    *reinterpret_cast<s8v*>(&Kt0[sk * 136 + sslot * 32 + j * 8]) = st[j];
  __syncthreads();
  for (int ch = 0; ch < NCH; ++ch) {
    unsigned short* const bufc = (ch & 1) ? Kt1 : Kt0;
    unsigned short* const bufn = (ch & 1) ? Kt0 : Kt1;
    const bool havenext = (ch + 1) < NCH;
    if (havenext) {
      const unsigned short* g = gk + (size_t)(ch + 1) * 64 * RANK;
#pragma unroll
      for (int j = 0; j < 4; ++j) st[j] = *reinterpret_cast<const s8v*>(&g[j * 8]);
    }
    f4v acc[4] = {};
#pragma unroll
    for (int kt = 0; kt < 4; ++kt) {
#pragma unroll
      for (int ks = 0; ks < 4; ++ks) {
        s8v a = *reinterpret_cast<const s8v*>(&bufc[(kt * 16 + l15) * 136 + ks * 32 + l4 * 8]);
        acc[kt] = mfma16(a, qf[ks], acc[kt]);
      }
    }
    // in-register selection: lane's scores are rows (r0+w*16+l15), keys kt*16+l4*4+r
    const int idb = kb0 + ch * 64 + l4 * 4;
#pragma unroll
    for (int kt = 0; kt < 4; ++kt) {
#pragma unroll
      for (int r = 0; r < 4; ++r) {
        const float v = acc[kt][r];
        if (v > bs[7]) {
          const int id = idb + kt * 16 + r;
#pragma unroll
          for (int k = 7; k >= 1; --k) {
            const bool keep = bs[k] >= v;
            const bool up = bs[k - 1] >= v;
            const float cand = up ? v : bs[k - 1];
            const int candi = up ? id : bi[k - 1];
            bs[k] = keep ? bs[k] : cand;
            bi[k] = keep ? bi[k] : candi;
          }
          if (bs[0] < v) { bs[0] = v; bi[0] = id; }
        }
      }
    }
    if (havenext) {
#pragma unroll
      for (int j = 0; j < 4; ++j)
        *reinterpret_cast<s8v*>(&bufn[sk * 136 + sslot * 32 + j * 8]) = st[j];
    }
    __syncthreads();
  }
  // merge the 4 lane-lists (l4=0..3) per row via LDS stash
  float* const mv = (float*)arena;                       // [64][33]
  int* const mi = (int*)(arena + 64 * 33 * 4);           // [64][33]
  const int row = w * 16 + l15;
#pragma unroll
  for (int k = 0; k < 8; ++k) {
    mv[row * 33 + l4 * 8 + k] = bs[k];
    mi[row * 33 + l4 * 8 + k] = bi[k];
  }
  __syncthreads();
  if (t < 64) {
    const int rr = t;
    int h0 = 0, h1 = 0, h2 = 0, h3 = 0;
    const size_t oo = ((size_t)sp * NROWS + r0 + rr) * TOPK;
    for (int k = 0; k < TOPK; ++k) {
      const float c0 = (h0 < 8) ? mv[rr * 33 + 0 + h0] : NEG_BIG;
      const float c1 = (h1 < 8) ? mv[rr * 33 + 8 + h1] : NEG_BIG;
      const float c2 = (h2 < 8) ? mv[rr * 33 + 16 + h2] : NEG_BIG;
      const float c3 = (h3 < 8) ? mv[rr * 33 + 24 + h3] : NEG_BIG;
      const float m01 = fmaxf(c0, c1); const int l01 = (c0 >= c1) ? 0 : 1;
      const float m23 = fmaxf(c2, c3); const int l23 = (c2 >= c3) ? 2 : 3;
      const float bv = fmaxf(m01, m23);
      const int bl = (m01 >= m23) ? l01 : l23;
      const int hb = (bl == 0) ? h0 : (bl == 1) ? h1 : (bl == 2) ? h2 : h3;
      const int idx = mi[rr * 33 + bl * 8 + hb];
      tks[oo + k] = bv;
      tki[oo + k] = idx;
      h0 += (bl == 0); h1 += (bl == 1); h2 += (bl == 2); h3 += (bl == 3);
    }
  }
}

// ---------------- merge splits (parallel rank-select), softmax, gather, out += mem ----------------
__global__ __launch_bounds__(256) void gather_kernel(const float* __restrict__ tks,
                                                     const int* __restrict__ tki,
                                                     const float* __restrict__ kV,
                                                     float* __restrict__ out) {
  __shared__ float ls[TK_SPLIT * TOPK];
  __shared__ int li[TK_SPLIT * TOPK];
  __shared__ float selv[TOPK];
  __shared__ int seli[TOPK];
  __shared__ float wsel[TOPK];
  const int row = blockIdx.x, t = threadIdx.x;
  if (t < TK_SPLIT * TOPK) {
    const int l = t >> 3, k = t & 7;
    ls[t] = tks[((size_t)l * NROWS + row) * TOPK + k];
    li[t] = tki[((size_t)l * NROWS + row) * TOPK + k];
  }
  __syncthreads();
  if (t < TK_SPLIT * TOPK) {
    const float v = ls[t];
    const int myid = li[t];
    int rank = 0;
    for (int j = 0; j < TK_SPLIT * TOPK; ++j) {
      const float u = ls[j];
      rank += (u > v) || (u == v && li[j] < myid);
    }
    if (rank < TOPK) { selv[rank] = v; seli[rank] = myid; }
  }
  __syncthreads();
  if (t == 0) {
    const float m = selv[0];
    float sum = 0.f, e[TOPK];
#pragma unroll
    for (int k = 0; k < TOPK; ++k) { e[k] = __expf(selv[k] - m); sum += e[k]; }
    const float inv = 1.f / sum;
#pragma unroll
    for (int k = 0; k < TOPK; ++k) wsel[k] = e[k] * inv;
  }
  __syncthreads();
  float4 accv = reinterpret_cast<float4*>(out + (size_t)row * DM)[t];
#pragma unroll
  for (int k = 0; k < TOPK; ++k) {
    const float4 v4 = reinterpret_cast<const float4*>(kV + (size_t)seli[k] * DM)[t];
    const float wk = wsel[k];
    accv.x += wk * v4.x; accv.y += wk * v4.y; accv.z += wk * v4.z; accv.w += wk * v4.w;
  }
  reinterpret_cast<float4*>(out + (size_t)row * DM)[t] = accv;
}

extern "C" void kernel_launch(void* const* d_in, const int* in_sizes, int n_in,
                              void* d_out, int out_size, void* d_ws, size_t ws_size,
                              hipStream_t stream) {
  (void)in_sizes; (void)n_in; (void)out_size; (void)ws_size;
  const float* x    = (const float*)d_in[0];
  const float* neur = (const float*)d_in[2];
  const float* kK   = (const float*)d_in[3];
  const float* kV   = (const float*)d_in[4];
  const float* rQ   = (const float*)d_in[5];
  const float* rK   = (const float*)d_in[6];
  const float* rV   = (const float*)d_in[7];
  const float* rM   = (const float*)d_in[8];
  const float* WQ   = (const float*)d_in[9];
  const float* WK   = (const float*)d_in[10];
  const float* WV   = (const float*)d_in[11];
  const float* WO   = (const float*)d_in[12];
  const float* g1   = (const float*)d_in[13];
  const float* b1   = (const float*)d_in[14];
  const float* g2   = (const float*)d_in[15];
  const float* b2   = (const float*)d_in[16];
  float* out = (float*)d_out;

  char* base = (char*)d_ws;
  auto alloc = [&](size_t bytes) { char* r = base; base += (bytes + 255) & ~(size_t)255; return r; };
  float*          h     = (float*)alloc((size_t)NROWS * DM * 4);
  unsigned short* hbf   = (unsigned short*)alloc((size_t)NROWS * DM * 2);  // reused as attn_bf
  float*          ap    = (float*)alloc((size_t)NROWS * NCMP * RANK * 4);  // reused as Q/K/V bf16
  unsigned short* neurT = (unsigned short*)alloc((size_t)NCMP * RANK * DM * 2);
  unsigned short* WQt   = (unsigned short*)alloc((size_t)DM * RANK * 2);
  unsigned short* WKt   = (unsigned short*)alloc((size_t)DM * RANK * 2);
  unsigned short* WVt   = (unsigned short*)alloc((size_t)DM * RANK * 2);
  unsigned short* WOt   = (unsigned short*)alloc((size_t)DM * DM * 2);
  unsigned short* kKb   = (unsigned short*)alloc((size_t)NKNOW * RANK * 2);
  unsigned short* hQb   = (unsigned short*)alloc((size_t)NROWS * RANK * 2);
  unsigned short* hKb   = (unsigned short*)alloc((size_t)NROWS * RANK * 2);
  unsigned short* hVb   = (unsigned short*)alloc((size_t)NROWS * RANK * 2);
  unsigned short* Qmb   = (unsigned short*)alloc((size_t)NROWS * RANK * 2);
  float* wQw = (float*)alloc((size_t)NROWS * NCMP * 4);
  float* wKw = (float*)alloc((size_t)NROWS * NCMP * 4);
  float* wVw = (float*)alloc((size_t)NROWS * NCMP * 4);
  float* wMw = (float*)alloc((size_t)NROWS * NCMP * 4);
  float* tks = (float*)alloc((size_t)TK_SPLIT * NROWS * TOPK * 4);
  int*   tki = (int*)alloc((size_t)TK_SPLIT * NROWS * TOPK * 4);
  unsigned short* Qb = (unsigned short*)ap;
  unsigned short* Kb = Qb + (size_t)NROWS * DM;
  unsigned short* Vb = Kb + (size_t)NROWS * DM;
  unsigned short* attnb = hbf;

  // one-time weight converts
  cvt_kernel<<<(NKNOW * RANK / 8 + 255) / 256, 256, 0, stream>>>(kK, kKb, NKNOW * RANK / 8);
  tcvt_kernel<<<dim3(RANK / 32, DM / 32, NCMP), 256, 0, stream>>>(neur, neurT, DM, RANK);
  tcvt_kernel<<<dim3(DM / 32, RANK / 32, 1), 256, 0, stream>>>(WQ, WQt, RANK, DM);
  tcvt_kernel<<<dim3(DM / 32, RANK / 32, 1), 256, 0, stream>>>(WK, WKt, RANK, DM);
  tcvt_kernel<<<dim3(DM / 32, RANK / 32, 1), 256, 0, stream>>>(WV, WVt, RANK, DM);
  tcvt_kernel<<<dim3(DM / 32, DM / 32, 1), 256, 0, stream>>>(WO, WOt, DM, DM);

  // ---- attention half ----
  ln_kernel<<<NROWS, 256, 0, stream>>>(x, g1, b1, h, hbf);
  mfma_nt<false, false><<<dim3(16, 32), 256, 0, stream>>>(hbf, neurT, ap, nullptr, nullptr,
                                                          NROWS, NCMP * RANK, DM);
  router3_kernel<<<NROWS, 256, 0, stream>>>(h, rQ, rK, rV, wQw, wKw, wVw);
  wsum_kernel<<<NROWS, 128, 0, stream>>>(ap, wQw, wKw, wVw, hQb, hKb, hVb, 1.0f);
  mfma_nt<true, false><<<dim3(8, 32), 256, 0, stream>>>(hQb, WQt, nullptr, Qb, nullptr,
                                                        NROWS, DM, RANK);
  mfma_nt<true, false><<<dim3(8, 32), 256, 0, stream>>>(hKb, WKt, nullptr, Kb, nullptr,
                                                        NROWS, DM, RANK);
  mfma_nt<true, false><<<dim3(8, 32), 256, 0, stream>>>(hVb, WVt, nullptr, Vb, nullptr,
                                                        NROWS, DM, RANK);
  flash_kernel<<<dim3(16, 64), 256, 0, stream>>>(Qb, Kb, Vb, attnb);
  mfma_nt<false, true><<<dim3(8, 32), 256, 0, stream>>>(attnb, WOt, out, nullptr, x,
                                                        NROWS, DM, DM);

  // ---- knowledge-memory half ----
  ln_kernel<<<NROWS, 256, 0, stream>>>(out, g2, b2, h, hbf);
  mfma_nt<false, false><<<dim3(16, 32), 256, 0, stream>>>(hbf, neurT, ap, nullptr, nullptr,
                                                          NROWS, NCMP * RANK, DM);
  router_kernel<<<NROWS, 256, 0, stream>>>(h, rM, wMw);
  wsum_kernel<<<NROWS, 128, 0, stream>>>(ap, wMw, nullptr, nullptr, Qmb, nullptr, nullptr,
                                         0.08838834764831845f /* 1/sqrt(128) */);
  topk_kernel<<<dim3(64, TK_SPLIT), 256, 0, stream>>>(Qmb, kKb, tks, tki);
  gather_kernel<<<NROWS, 256, 0, stream>>>(tks, tki, kV, out);
}